// Round 10
// baseline (2876.902 us; speedup 1.0000x reference)
//
#include <hip/hip_runtime.h>
#include <hip/hip_bf16.h>

typedef unsigned short u16;
typedef __attribute__((ext_vector_type(8))) short bhalf8;
typedef __attribute__((ext_vector_type(4))) short bhalf4;
typedef __attribute__((ext_vector_type(4))) float f32x4;

__device__ inline f32x4 mfma_bf16(bhalf8 a, bhalf8 b, f32x4 c) {
    return __builtin_amdgcn_mfma_f32_16x16x32_bf16(a, b, c, 0, 0, 0);
}
__device__ inline f32x4 mfma16_bf16(bhalf4 a, bhalf4 b, f32x4 c) {
    return __builtin_amdgcn_mfma_f32_16x16x16bf16_1k(a, b, c, 0, 0, 0);
}

__device__ inline u16 f2bf(float f) {
    union { float f; unsigned u; } v; v.f = f;
    unsigned u = v.u;
    return (u16)((u + 0x7fff + ((u >> 16) & 1)) >> 16);
}
__device__ inline unsigned pkbf(float lo_, float hi_) {
    return ((unsigned)f2bf(hi_) << 16) | (unsigned)f2bf(lo_);
}
// native packed f32x2 -> bf16x2 (RNE; identical rounding to f2bf on finite vals)
__device__ inline unsigned pk2bf(float lo, float hi) {
    union { __hip_bfloat162 h; unsigned u; } v;
    v.h = __float22bfloat162_rn(float2{lo, hi});
    return v.u;
}

// Fragment-major (afm) layout for [M][C] bf16: tile t=row>>4, chunk kc=col>>5,
// lane' = (row&15) + 16*((col>>3)&3), elem i = col&7.
__device__ inline size_t afm_off(int row, int col, int Cc) {
    return ((size_t)((row >> 4) * Cc + (col >> 5))) * 512
         + (((row & 15) + 16 * ((col >> 3) & 3)) << 3) + (col & 7);
}

// ---------------- prologue kernels ----------------

__global__ __launch_bounds__(256) void k_wtrans_fm(const float* in, u16* out, int rows, int cols) {
    int mat = blockIdx.y;
    size_t rc = (size_t)rows * cols;
    size_t idx = (size_t)blockIdx.x * 256 + threadIdx.x;
    if (idx >= rc) return;
    int r = (int)(idx / cols), c = (int)(idx % cols);   // r=k, c=n
    size_t off = ((size_t)((c >> 4) * (rows >> 5) + (r >> 5))) * 512
               + (((c & 15) + 16 * ((r >> 3) & 3)) << 3) + (r & 7);
    out[mat * rc + off] = f2bf(in[mat * rc + idx]);
}

__global__ __launch_bounds__(256) void k_addpos(const float* x, const float* pos, u16* xp) {
    size_t idx = (size_t)blockIdx.x * 256 + threadIdx.x;
    size_t p = idx & ((size_t)4096 * 256 - 1);
    int row = (int)(idx >> 8), col = (int)(idx & 255);
    xp[afm_off(row, col, 8)] = f2bf(x[idx] + pos[p]);
}

__global__ __launch_bounds__(256) void k_inith(const float* y, float* h, u16* hb) {
    size_t idx = (size_t)blockIdx.x * 256 + threadIdx.x;
    float v = y[idx];
    h[idx] = v;
    int row = (int)(idx >> 8), col = (int)(idx & 255);
    hb[afm_off(row, col, 8)] = f2bf(v);
}

// ---------------- precompute cross K/V for ALL layers (layer-invariant A=xp) ----
// Round-8 proven version (43.8µs): FUSED K+V, blockIdx.z = layer; each block
// loads its A rows once and applies both W_k and W_v (4 accs, 4 MFMAs/kc).
// (Round-9 LDS-staged variant reverted: 172 VGPR + 64KB LDS -> 9% occupancy.)
__global__ __launch_bounds__(256) void k_kv_pre(const u16* A2, const u16* Wall, const float* ball,
                                                u16* kfm_all, u16* vfm_all) {
    const int Skv = 4096;
    int layer = blockIdx.z;
    int wave = threadIdx.x >> 6, lane = threadIdx.x & 63;
    int l16 = lane & 15, quad = lane >> 4;
    int row0 = blockIdx.x * 64 + wave * 16;
    int col0 = blockIdx.y * 32;
    const u16* Wk = Wall + (size_t)layer * 3 * 65536 + 65536;
    const u16* Wv = Wk + 65536;
    const float* bk = ball + layer * 768 + 256;
    const float* bv = bk + 256;
    u16* kout = kfm_all + (size_t)layer * 2097152;
    u16* vout = vfm_all + (size_t)layer * 2097152;
    const int Kc = 8;

    f32x4 acck0 = (f32x4){0.f, 0.f, 0.f, 0.f};
    f32x4 acck1 = (f32x4){0.f, 0.f, 0.f, 0.f};
    f32x4 accv0 = (f32x4){0.f, 0.f, 0.f, 0.f};
    f32x4 accv1 = (f32x4){0.f, 0.f, 0.f, 0.f};
    const u16* ab  = A2 + (size_t)(row0 >> 4) * Kc * 512 + lane * 8;
    const u16* wk0 = Wk + (size_t)(col0 >> 4) * Kc * 512 + lane * 8;
    const u16* wk1 = wk0 + (size_t)Kc * 512;
    const u16* wv0 = Wv + (size_t)(col0 >> 4) * Kc * 512 + lane * 8;
    const u16* wv1 = wv0 + (size_t)Kc * 512;
    #pragma unroll
    for (int kc = 0; kc < Kc; kc++) {
        bhalf8 a = *(const bhalf8*)(ab + kc * 512);
        acck0 = mfma_bf16(a, *(const bhalf8*)(wk0 + kc * 512), acck0);
        acck1 = mfma_bf16(a, *(const bhalf8*)(wk1 + kc * 512), acck1);
        accv0 = mfma_bf16(a, *(const bhalf8*)(wv0 + kc * 512), accv0);
        accv1 = mfma_bf16(a, *(const bhalf8*)(wv1 + kc * 512), accv1);
    }

    // ---- K epilogue (verbatim) ----
    {
        f32x4 accs[2] = {acck0, acck1};
        #pragma unroll
        for (int nt = 0; nt < 2; nt++) {
            int col = col0 + nt * 16 + l16;
            float bs = bk[col];
            int hh = col >> 6, dim = col & 63;
            int f = dim >> 5, q8 = (dim >> 3) & 3, i8 = dim & 7;
            #pragma unroll
            for (int r = 0; r < 4; r++) {
                int row = row0 + quad * 4 + r;
                int bb = row / Skv; int key = row - bb * Skv;
                size_t off = (size_t)(bb * 4 + hh) * Skv * 64 + (size_t)(key >> 4) * 1024
                           + f * 512 + q8 * 128 + (key & 15) * 8 + i8;
                kout[off] = f2bf(accs[nt][r] + bs);
            }
        }
    }
    // ---- V epilogue (verbatim) ----
    {
        f32x4 accs[2] = {accv0, accv1};
        #pragma unroll
        for (int nt = 0; nt < 2; nt++) {
            int col = col0 + nt * 16 + l16;
            float bs = bv[col];
            int hh = col >> 6, dim = col & 63;
            int ntg = dim >> 4, l16v = dim & 15;
            int row = row0 + quad * 4;
            int bb = row / Skv; int key = row - bb * Skv;
            size_t off = (size_t)(bb * 4 + hh) * Skv * 64 + (size_t)(key >> 4) * 1024
                       + ntg * 256 + ((key & 15) >> 2) * 64 + l16v * 4;
            ushort4 pk;
            pk.x = f2bf(accs[nt][0] + bs);
            pk.y = f2bf(accs[nt][1] + bs);
            pk.z = f2bf(accs[nt][2] + bs);
            pk.w = f2bf(accs[nt][3] + bs);
            *(ushort4*)(vout + off) = pk;
        }
    }
}

// ---------------- QKV GEMM (all operands fragment-major) ----------------
__global__ __launch_bounds__(256) void k_gemm_qkv(const u16* A0, const u16* A2,
                                                  const u16* Wfm0, const float* bias0,
                                                  u16* qout, u16* kfm_out, u16* vfm_out,
                                                  int K, long wz, long bz, float scale0,
                                                  int kz, int vz, int Skv, int M0) {
    int z = blockIdx.z;
    int wave = threadIdx.x >> 6, lane = threadIdx.x & 63;
    int l16 = lane & 15, quad = lane >> 4;
    int row0 = blockIdx.x * 64 + wave * 16;
    int col0 = blockIdx.y * 32;
    const u16* A;
    if (z == 0) { if (row0 >= M0) return; A = A0; } else { A = A2; }
    const u16* Wfm = Wfm0 + (size_t)z * wz;
    const float* bias = bias0 + (size_t)z * bz;
    int Kc = K >> 5;

    f32x4 acc0 = (f32x4){0.f, 0.f, 0.f, 0.f};
    f32x4 acc1 = (f32x4){0.f, 0.f, 0.f, 0.f};
    const u16* ab = A + (size_t)(row0 >> 4) * Kc * 512 + lane * 8;
    const u16* wb0 = Wfm + (size_t)(col0 >> 4) * Kc * 512 + lane * 8;
    const u16* wb1 = wb0 + (size_t)Kc * 512;
    #pragma unroll 4
    for (int kc = 0; kc < Kc; kc++) {
        bhalf8 a = *(const bhalf8*)(ab + kc * 512);
        acc0 = mfma_bf16(a, *(const bhalf8*)(wb0 + kc * 512), acc0);
        acc1 = mfma_bf16(a, *(const bhalf8*)(wb1 + kc * 512), acc1);
    }

    f32x4 accs[2] = {acc0, acc1};
    #pragma unroll
    for (int nt = 0; nt < 2; nt++) {
        int col = col0 + nt * 16 + l16;
        float bs = bias[col];
        if (z == kz) {
            int hh = col >> 6, dim = col & 63;
            int f = dim >> 5, q8 = (dim >> 3) & 3, i8 = dim & 7;
            #pragma unroll
            for (int r = 0; r < 4; r++) {
                int row = row0 + quad * 4 + r;
                int bb = row / Skv; int key = row - bb * Skv;
                size_t off = (size_t)(bb * 4 + hh) * Skv * 64 + (size_t)(key >> 4) * 1024
                           + f * 512 + q8 * 128 + (key & 15) * 8 + i8;
                kfm_out[off] = f2bf(accs[nt][r] + bs);
            }
        } else if (z == vz) {
            int hh = col >> 6, dim = col & 63;
            int ntg = dim >> 4, l16v = dim & 15;
            int row = row0 + quad * 4;
            int bb = row / Skv; int key = row - bb * Skv;
            size_t off = (size_t)(bb * 4 + hh) * Skv * 64 + (size_t)(key >> 4) * 1024
                       + ntg * 256 + ((key & 15) >> 2) * 64 + l16v * 4;
            ushort4 pk;
            pk.x = f2bf(accs[nt][0] + bs);
            pk.y = f2bf(accs[nt][1] + bs);
            pk.z = f2bf(accs[nt][2] + bs);
            pk.w = f2bf(accs[nt][3] + bs);
            *(ushort4*)(vfm_out + off) = pk;
        } else {
            size_t base = ((size_t)(row0 >> 4) * 8 + blockIdx.y) * 512;
            int g3 = (nt * 2 + (l16 >> 3)) & 3;
            int i = l16 & 7;
            #pragma unroll
            for (int r = 0; r < 4; r++)
                qout[base + (((quad * 4 + r) + 16 * g3) << 3) + i] =
                    f2bf((accs[nt][r] + bs) * scale0);
        }
    }
}

// ---------------- GEMM + bias + residual + LayerNorm (8 waves) ----------------
// Block 512 thr = 8 waves; each wave: same 16 rows, 2 n-tiles (32 cols).
// LN stats merged across waves via LDS. outf fp32 row-major, outb bf16 afm.
__global__ __launch_bounds__(512) void k_gemm_ln(const u16* A, const u16* Wfm, const float* bias,
                                                 const float* res, const float* g, const float* beta,
                                                 float* outf, u16* outb, int K) {
    int t = threadIdx.x;
    int w = t >> 6, lane = t & 63;
    int l16 = lane & 15, quad = lane >> 4;
    int row0 = blockIdx.x * 16;
    int Kc = K >> 5;

    f32x4 acc[2];
    acc[0] = (f32x4){0.f, 0.f, 0.f, 0.f};
    acc[1] = (f32x4){0.f, 0.f, 0.f, 0.f};

    const u16* ab = A + (size_t)blockIdx.x * Kc * 512 + lane * 8;
    const u16* wb = Wfm + (size_t)(w * 2) * Kc * 512 + lane * 8;
    #pragma unroll 4
    for (int kc = 0; kc < Kc; kc++) {
        bhalf8 a = *(const bhalf8*)(ab + kc * 512);
        acc[0] = mfma_bf16(a, *(const bhalf8*)(wb + kc * 512), acc[0]);
        acc[1] = mfma_bf16(a, *(const bhalf8*)(wb + (size_t)(Kc + kc) * 512), acc[1]);
    }

    float sr[4] = {0.f, 0.f, 0.f, 0.f}, s2r[4] = {0.f, 0.f, 0.f, 0.f};
    #pragma unroll
    for (int nt = 0; nt < 2; nt++) {
        int col = w * 32 + nt * 16 + l16;
        float bs = bias[col];
        #pragma unroll
        for (int r = 0; r < 4; r++) {
            int row = row0 + quad * 4 + r;
            float v = acc[nt][r] + bs + res[(size_t)row * 256 + col];
            acc[nt][r] = v;
            sr[r] += v; s2r[r] += v * v;
        }
    }
    #pragma unroll
    for (int r = 0; r < 4; r++) {
        #pragma unroll
        for (int off = 8; off >= 1; off >>= 1) {
            sr[r]  += __shfl_xor(sr[r], off, 16);
            s2r[r] += __shfl_xor(s2r[r], off, 16);
        }
    }
    __shared__ float lsm[8][16], lsq[8][16];
    if (l16 == 0) {
        #pragma unroll
        for (int r = 0; r < 4; r++) { lsm[w][quad * 4 + r] = sr[r]; lsq[w][quad * 4 + r] = s2r[r]; }
    }
    __syncthreads();
    float mu[4], rs[4];
    #pragma unroll
    for (int r = 0; r < 4; r++) {
        int ri = quad * 4 + r;
        float ts = 0.f, tq = 0.f;
        #pragma unroll
        for (int ww = 0; ww < 8; ww++) { ts += lsm[ww][ri]; tq += lsq[ww][ri]; }
        mu[r] = ts * (1.f / 256.f);
        float var = tq * (1.f / 256.f) - mu[r] * mu[r];
        rs[r] = rsqrtf(var + 1e-12f);
    }
    size_t base = ((size_t)blockIdx.x * 8 + w) * 512;
    #pragma unroll
    for (int nt = 0; nt < 2; nt++) {
        int col = w * 32 + nt * 16 + l16;
        float gc = g[col], bc = beta[col];
        int g3 = (nt * 2 + (l16 >> 3)) & 3;
        int i = l16 & 7;
        #pragma unroll
        for (int r = 0; r < 4; r++) {
            int row = row0 + quad * 4 + r;
            float yv = (acc[nt][r] - mu[r]) * rs[r] * gc + bc;
            outf[(size_t)row * 256 + col] = yv;
            outb[base + (((quad * 4 + r) + 16 * g3) << 3) + i] = f2bf(yv);
        }
    }
}

// ---------------- fused FFN: GEMM1+GELU -> LDS -> GEMM2 + res + LN -----------
__global__ __launch_bounds__(512) void k_ffn(const u16* A, const u16* W1, const float* b1,
                                             const u16* W2, const float* b2,
                                             const float* res, const float* g, const float* beta,
                                             float* outf, u16* outb) {
    int t = threadIdx.x;
    int w = t >> 6, lane = t & 63;
    int l16 = lane & 15, quad = lane >> 4;
    int row0 = blockIdx.x * 16;

    __shared__ u16 f1lds[32 * 512];    // 32 chunks x 512 u16 = 32 KB (afm, K=1024)
    __shared__ float lsm[8][16], lsq[8][16];

    // ---- stage 1: f1 = A @ W1 (K=256, Kc=8), wave w -> 8 n-tiles ----
    f32x4 acc[8];
    #pragma unroll
    for (int nt = 0; nt < 8; nt++) acc[nt] = (f32x4){0.f, 0.f, 0.f, 0.f};
    const u16* ab = A + (size_t)blockIdx.x * 8 * 512 + lane * 8;
    const u16* w1b = W1 + (size_t)(w * 8) * 8 * 512 + lane * 8;
    #pragma unroll
    for (int kc = 0; kc < 8; kc++) {
        bhalf8 a = *(const bhalf8*)(ab + kc * 512);
        #pragma unroll
        for (int nt = 0; nt < 8; nt++)
            acc[nt] = mfma_bf16(a, *(const bhalf8*)(w1b + ((size_t)nt * 8 + kc) * 512), acc[nt]);
    }
    // GELU + pack to LDS afm
    #pragma unroll
    for (int nt = 0; nt < 8; nt++) {
        int col = w * 128 + nt * 16 + l16;
        float bs = b1[col];
        int chunk = w * 4 + (nt >> 1);
        int g3 = (nt * 2 + (l16 >> 3)) & 3;
        int i = l16 & 7;
        #pragma unroll
        for (int r = 0; r < 4; r++) {
            float v = acc[nt][r] + bs;
            float ge = 0.5f * v * (1.f + tanhf(0.7978845608028654f * (v + 0.044715f * v * v * v)));
            f1lds[chunk * 512 + (((quad * 4 + r) + 16 * g3) << 3) + i] = f2bf(ge);
        }
    }
    __syncthreads();

    // ---- stage 2: out = f1 @ W2 (K=1024, Kc=32), wave w -> 2 n-tiles ----
    f32x4 acc2[2];
    acc2[0] = (f32x4){0.f, 0.f, 0.f, 0.f};
    acc2[1] = (f32x4){0.f, 0.f, 0.f, 0.f};
    const u16* w2b = W2 + (size_t)(w * 2) * 32 * 512 + lane * 8;
    #pragma unroll 4
    for (int kc = 0; kc < 32; kc++) {
        bhalf8 a = *(const bhalf8*)&f1lds[kc * 512 + lane * 8];
        acc2[0] = mfma_bf16(a, *(const bhalf8*)(w2b + (size_t)kc * 512), acc2[0]);
        acc2[1] = mfma_bf16(a, *(const bhalf8*)(w2b + (size_t)(32 + kc) * 512), acc2[1]);
    }

    // ---- stage 3: bias + residual + LN ----
    float sr[4] = {0.f, 0.f, 0.f, 0.f}, s2r[4] = {0.f, 0.f, 0.f, 0.f};
    #pragma unroll
    for (int nt = 0; nt < 2; nt++) {
        int col = w * 32 + nt * 16 + l16;
        float bs = b2[col];
        #pragma unroll
        for (int r = 0; r < 4; r++) {
            int row = row0 + quad * 4 + r;
            float v = acc2[nt][r] + bs + res[(size_t)row * 256 + col];
            acc2[nt][r] = v;
            sr[r] += v; s2r[r] += v * v;
        }
    }
    #pragma unroll
    for (int r = 0; r < 4; r++) {
        #pragma unroll
        for (int off = 8; off >= 1; off >>= 1) {
            sr[r]  += __shfl_xor(sr[r], off, 16);
            s2r[r] += __shfl_xor(s2r[r], off, 16);
        }
    }
    if (l16 == 0) {
        #pragma unroll
        for (int r = 0; r < 4; r++) { lsm[w][quad * 4 + r] = sr[r]; lsq[w][quad * 4 + r] = s2r[r]; }
    }
    __syncthreads();
    float mu[4], rs[4];
    #pragma unroll
    for (int r = 0; r < 4; r++) {
        int ri = quad * 4 + r;
        float ts = 0.f, tq = 0.f;
        #pragma unroll
        for (int ww = 0; ww < 8; ww++) { ts += lsm[ww][ri]; tq += lsq[ww][ri]; }
        mu[r] = ts * (1.f / 256.f);
        float var = tq * (1.f / 256.f) - mu[r] * mu[r];
        rs[r] = rsqrtf(var + 1e-12f);
    }
    size_t base = ((size_t)blockIdx.x * 8 + w) * 512;
    #pragma unroll
    for (int nt = 0; nt < 2; nt++) {
        int col = w * 32 + nt * 16 + l16;
        float gc = g[col], bc = beta[col];
        int g3 = (nt * 2 + (l16 >> 3)) & 3;
        int i = l16 & 7;
        #pragma unroll
        for (int r = 0; r < 4; r++) {
            int row = row0 + quad * 4 + r;
            float yv = (acc2[nt][r] - mu[r]) * rs[r] * gc + bc;
            outf[(size_t)row * 256 + col] = yv;
            outb[base + (((quad * 4 + r) + 16 * g3) << 3) + i] = f2bf(yv);
        }
    }
}

// ---------------- flash attention, q-major (fragment-major Q/K/V, afm ctx out) --
// NEW decomposition: 256 thr = 4 waves; wave w owns ONE 16-row q-tile
// (qp*4+w) and sweeps ALL keys (valid because softmax uses a FIXED exponent
// offset — no running max -> no cross-wave combine, no LDS, no tail).
// All 4 waves read the SAME K/V stream; __syncthreads every 4 tiles (16KB
// <= L1) keeps them in lockstep so L1 serves 3 of 4 waves. Distinct traffic
// per block = Sk*256B -> cross 256 MB (2x cut), self 128 MB (2x cut).
// Inner-loop math byte-identical (pk2bf/exp2f/MFMA); store = old kw==0 path.
__global__ __launch_bounds__(256, 4) void k_attn(const u16* q, const u16* kfm, const u16* vfm,
                                                 u16* ctx, int Sq, int Sk) {
    int bh = blockIdx.x & 7;
    int b = bh >> 2, h = bh & 3;
    int qp = blockIdx.x >> 3;
    int t = threadIdx.x;
    int w = t >> 6, lane = t & 63;
    int l16 = lane & 15, quad = lane >> 4;
    int q0 = qp * 64 + w * 16;

    size_t rt0 = (size_t)((b * Sq + q0) >> 4);
    const u16* qb = q + (rt0 * 8 + h * 2) * 512 + lane * 8;
    bhalf8 bq0 = *(const bhalf8*)(qb);
    bhalf8 bq1 = *(const bhalf8*)(qb + 512);

    const u16* kt = kfm + (size_t)(b * 4 + h) * Sk * 64 + lane * 8;
    const u16* vt = vfm + (size_t)(b * 4 + h) * Sk * 64 + quad * 64 + l16 * 4;

    int nT = Sk >> 4;          // ALL 16-key tiles (full sweep, no key split)

    float l = 0.f;
    f32x4 o[4];
    #pragma unroll
    for (int nt = 0; nt < 4; nt++) o[nt] = (f32x4){0.f, 0.f, 0.f, 0.f};

    for (int Tb = 0; Tb < nT; Tb += 4) {
        __syncthreads();       // lockstep the 4 waves within a 16KB window
        #pragma unroll
        for (int u = 0; u < 4; u++) {
            bhalf8 a0 = *(const bhalf8*)(kt);
            bhalf8 a1 = *(const bhalf8*)(kt + 512);
            f32x4 s = (f32x4){0.f, 0.f, 0.f, 0.f};
            s = mfma_bf16(a0, bq0, s);
            s = mfma_bf16(a1, bq1, s);

            float p0 = exp2f(s[0] - 11.5415603f);
            float p1 = exp2f(s[1] - 11.5415603f);
            float p2 = exp2f(s[2] - 11.5415603f);
            float p3 = exp2f(s[3] - 11.5415603f);
            l += (p0 + p1) + (p2 + p3);

            union { bhalf4 v; unsigned uu[2]; } bp;
            bp.uu[0] = pk2bf(p0, p1);
            bp.uu[1] = pk2bf(p2, p3);

            #pragma unroll
            for (int nt = 0; nt < 4; nt++) {
                bhalf4 va = *(const bhalf4*)(vt + nt * 256);
                o[nt] = mfma16_bf16(va, bp.v, o[nt]);
            }
            kt += 1024;
            vt += 1024;
        }
    }

    float lc = l;
    lc += __shfl_xor(lc, 16, 64);
    lc += __shfl_xor(lc, 32, 64);
    float invL = 1.f / lc;

    #pragma unroll
    for (int nt = 0; nt < 4; nt++) {
        ushort4 pkv;
        #pragma unroll
        for (int r = 0; r < 4; r++)
            ((u16*)&pkv)[r] = f2bf(o[nt][r] * invL);
        size_t ce = ((l16 + 16 * ((nt * 2 + (quad >> 1)) & 3)) << 3) + (quad & 1) * 4;
        size_t off = (rt0 * 8 + (h * 2 + (nt >> 1))) * 512 + ce;
        *(ushort4*)(ctx + off) = pkv;
    }
}

// ---------------- host ----------------
extern "C" void kernel_launch(void* const* d_in, const int* in_sizes, int n_in,
                              void* d_out, int out_size, void* d_ws, size_t ws_size,
                              hipStream_t stream) {
    const float* x        = (const float*)d_in[0];
    const float* y        = (const float*)d_in[1];
    const float* pos      = (const float*)d_in[2];
    const float* sqkv_w   = (const float*)d_in[3];
    const float* sqkv_b   = (const float*)d_in[4];
    const float* so_w     = (const float*)d_in[5];
    const float* so_b     = (const float*)d_in[6];
    const float* cqkv_w   = (const float*)d_in[7];
    const float* cqkv_b   = (const float*)d_in[8];
    const float* co_w     = (const float*)d_in[9];
    const float* co_b     = (const float*)d_in[10];
    const float* ffn_w1   = (const float*)d_in[11];
    const float* ffn_b1   = (const float*)d_in[12];
    const float* ffn_w2   = (const float*)d_in[13];
    const float* ffn_b2   = (const float*)d_in[14];
    const float* ln_g     = (const float*)d_in[15];
    const float* ln_b     = (const float*)d_in[16];

    char* w = (char*)d_ws;
    auto alloc = [&](size_t bytes) { char* p = w; w += (bytes + 255) & ~(size_t)255; return p; };

    u16* wt_sqkv = (u16*)alloc(18ull * 65536 * 2);
    u16* wt_so   = (u16*)alloc(6ull  * 65536 * 2);
    u16* wt_cqkv = (u16*)alloc(18ull * 65536 * 2);
    u16* wt_co   = (u16*)alloc(6ull  * 65536 * 2);
    u16* wt_f1   = (u16*)alloc(6ull  * 262144 * 2);
    u16* wt_f2   = (u16*)alloc(6ull  * 262144 * 2);
    u16* xp      = (u16*)alloc(2097152ull * 2);
    float* hf    = (float*)alloc(1048576ull * 4);
    u16* hb      = (u16*)alloc(1048576ull * 2);
    u16* qbuf    = (u16*)alloc(1048576ull * 2);
    u16* kfm     = (u16*)alloc(2097152ull * 2);
    u16* vfm     = (u16*)alloc(2097152ull * 2);
    u16* ctx     = (u16*)alloc(1048576ull * 2);
    u16* kfm_all = (u16*)alloc(6ull * 2097152 * 2);   // per-layer cross K (24 MB)
    u16* vfm_all = (u16*)alloc(6ull * 2097152 * 2);   // per-layer cross V (24 MB)

    k_wtrans_fm<<<dim3(256, 18), 256, 0, stream>>>(sqkv_w, wt_sqkv, 256, 256);
    k_wtrans_fm<<<dim3(256, 6),  256, 0, stream>>>(so_w,   wt_so,   256, 256);
    k_wtrans_fm<<<dim3(256, 18), 256, 0, stream>>>(cqkv_w, wt_cqkv, 256, 256);
    k_wtrans_fm<<<dim3(256, 6),  256, 0, stream>>>(co_w,   wt_co,   256, 256);
    k_wtrans_fm<<<dim3(1024, 6), 256, 0, stream>>>(ffn_w1, wt_f1,   256, 1024);
    k_wtrans_fm<<<dim3(1024, 6), 256, 0, stream>>>(ffn_w2, wt_f2,   1024, 256);
    k_addpos<<<dim3(8192), 256, 0, stream>>>(x, pos, xp);
    k_inith<<<dim3(4096), 256, 0, stream>>>(y, hf, hb);
    // cross K/V for all 6 layers: layer-invariant A=xp, fused K+V per block
    k_kv_pre<<<dim3(128, 8, 6), 256, 0, stream>>>(xp, wt_cqkv, cqkv_b, kfm_all, vfm_all);

    const float qscale = 0.125f * 1.44269504f;  // 1/sqrt(64) * log2(e)

    for (int i = 0; i < 6; i++) {
        // ---- self attention ----
        k_gemm_qkv<<<dim3(64, 8, 3), 256, 0, stream>>>(hb, hb,
            wt_sqkv + (size_t)i * 3 * 65536, sqkv_b + i * 768,
            qbuf, kfm, vfm, 256, 65536, 256, qscale, 1, 2, 2048, 4096);
        k_attn<<<dim3(256), 256, 0, stream>>>(qbuf, kfm, vfm, ctx, 2048, 2048);
        k_gemm_ln<<<dim3(256), 512, 0, stream>>>(ctx, wt_so + (size_t)i * 65536,
            so_b + i * 256, hf, ln_g + (i * 3 + 0) * 256, ln_b + (i * 3 + 0) * 256,
            hf, hb, 256);

        // ---- cross attention (K/V precomputed; only q GEMM in-loop) ----
        k_gemm_qkv<<<dim3(64, 8, 1), 256, 0, stream>>>(hb, xp,
            wt_cqkv + (size_t)i * 3 * 65536, cqkv_b + i * 768,
            qbuf, kfm, vfm, 256, 65536, 256, qscale, 1, 2, 4096, 4096);
        k_attn<<<dim3(256), 256, 0, stream>>>(qbuf,
            kfm_all + (size_t)i * 2097152, vfm_all + (size_t)i * 2097152, ctx, 2048, 4096);
        k_gemm_ln<<<dim3(256), 512, 0, stream>>>(ctx, wt_co + (size_t)i * 65536,
            co_b + i * 256, hf, ln_g + (i * 3 + 1) * 256, ln_b + (i * 3 + 1) * 256,
            hf, hb, 256);

        // ---- fused FFN ----
        float* dst = (i == 5) ? (float*)d_out : hf;
        k_ffn<<<dim3(256), 512, 0, stream>>>(hb, wt_f1 + (size_t)i * 262144,
            ffn_b1 + i * 1024, wt_f2 + (size_t)i * 262144, ffn_b2 + i * 256,
            hf, ln_g + (i * 3 + 2) * 256, ln_b + (i * 3 + 2) * 256, dst, hb);
    }
}

// Round 11
// 905.294 us; speedup vs baseline: 3.1779x; 3.1779x over previous
//
#include <hip/hip_runtime.h>
#include <hip/hip_bf16.h>

typedef unsigned short u16;
typedef __attribute__((ext_vector_type(8))) short bhalf8;
typedef __attribute__((ext_vector_type(4))) short bhalf4;
typedef __attribute__((ext_vector_type(4))) float f32x4;

__device__ inline f32x4 mfma_bf16(bhalf8 a, bhalf8 b, f32x4 c) {
    return __builtin_amdgcn_mfma_f32_16x16x32_bf16(a, b, c, 0, 0, 0);
}
__device__ inline f32x4 mfma16_bf16(bhalf4 a, bhalf4 b, f32x4 c) {
    return __builtin_amdgcn_mfma_f32_16x16x16bf16_1k(a, b, c, 0, 0, 0);
}

__device__ inline u16 f2bf(float f) {
    union { float f; unsigned u; } v; v.f = f;
    unsigned u = v.u;
    return (u16)((u + 0x7fff + ((u >> 16) & 1)) >> 16);
}
// native packed f32x2 -> bf16x2 (RNE; identical rounding to f2bf on finite vals)
__device__ inline unsigned pk2bf(float lo, float hi) {
    union { __hip_bfloat162 h; unsigned u; } v;
    v.h = __float22bfloat162_rn(float2{lo, hi});
    return v.u;
}

// Fragment-major (afm) layout for [M][C] bf16: tile t=row>>4, chunk kc=col>>5,
// lane' = (row&15) + 16*((col>>3)&3), elem i = col&7.
__device__ inline size_t afm_off(int row, int col, int Cc) {
    return ((size_t)((row >> 4) * Cc + (col >> 5))) * 512
         + (((row & 15) + 16 * ((col >> 3) & 3)) << 3) + (col & 7);
}

// ---------------- prologue kernels ----------------

__global__ __launch_bounds__(256) void k_wtrans_fm(const float* in, u16* out, int rows, int cols) {
    int mat = blockIdx.y;
    size_t rc = (size_t)rows * cols;
    size_t idx = (size_t)blockIdx.x * 256 + threadIdx.x;
    if (idx >= rc) return;
    int r = (int)(idx / cols), c = (int)(idx % cols);   // r=k, c=n
    size_t off = ((size_t)((c >> 4) * (rows >> 5) + (r >> 5))) * 512
               + (((c & 15) + 16 * ((r >> 3) & 3)) << 3) + (r & 7);
    out[mat * rc + off] = f2bf(in[mat * rc + idx]);
}

__global__ __launch_bounds__(256) void k_addpos(const float* x, const float* pos, u16* xp) {
    size_t idx = (size_t)blockIdx.x * 256 + threadIdx.x;
    size_t p = idx & ((size_t)4096 * 256 - 1);
    int row = (int)(idx >> 8), col = (int)(idx & 255);
    xp[afm_off(row, col, 8)] = f2bf(x[idx] + pos[p]);
}

__global__ __launch_bounds__(256) void k_inith(const float* y, float* h, u16* hb) {
    size_t idx = (size_t)blockIdx.x * 256 + threadIdx.x;
    float v = y[idx];
    h[idx] = v;
    int row = (int)(idx >> 8), col = (int)(idx & 255);
    hb[afm_off(row, col, 8)] = f2bf(v);
}

// ---------------- precompute cross K/V for ALL layers (layer-invariant A=xp) ----
// Round-8 proven version (43.8µs): FUSED K+V, blockIdx.z = layer; each block
// loads its A rows once and applies both W_k and W_v (4 accs, 4 MFMAs/kc).
__global__ __launch_bounds__(256) void k_kv_pre(const u16* A2, const u16* Wall, const float* ball,
                                                u16* kfm_all, u16* vfm_all) {
    const int Skv = 4096;
    int layer = blockIdx.z;
    int wave = threadIdx.x >> 6, lane = threadIdx.x & 63;
    int l16 = lane & 15, quad = lane >> 4;
    int row0 = blockIdx.x * 64 + wave * 16;
    int col0 = blockIdx.y * 32;
    const u16* Wk = Wall + (size_t)layer * 3 * 65536 + 65536;
    const u16* Wv = Wk + 65536;
    const float* bk = ball + layer * 768 + 256;
    const float* bv = bk + 256;
    u16* kout = kfm_all + (size_t)layer * 2097152;
    u16* vout = vfm_all + (size_t)layer * 2097152;
    const int Kc = 8;

    f32x4 acck0 = (f32x4){0.f, 0.f, 0.f, 0.f};
    f32x4 acck1 = (f32x4){0.f, 0.f, 0.f, 0.f};
    f32x4 accv0 = (f32x4){0.f, 0.f, 0.f, 0.f};
    f32x4 accv1 = (f32x4){0.f, 0.f, 0.f, 0.f};
    const u16* ab  = A2 + (size_t)(row0 >> 4) * Kc * 512 + lane * 8;
    const u16* wk0 = Wk + (size_t)(col0 >> 4) * Kc * 512 + lane * 8;
    const u16* wk1 = wk0 + (size_t)Kc * 512;
    const u16* wv0 = Wv + (size_t)(col0 >> 4) * Kc * 512 + lane * 8;
    const u16* wv1 = wv0 + (size_t)Kc * 512;
    #pragma unroll
    for (int kc = 0; kc < Kc; kc++) {
        bhalf8 a = *(const bhalf8*)(ab + kc * 512);
        acck0 = mfma_bf16(a, *(const bhalf8*)(wk0 + kc * 512), acck0);
        acck1 = mfma_bf16(a, *(const bhalf8*)(wk1 + kc * 512), acck1);
        accv0 = mfma_bf16(a, *(const bhalf8*)(wv0 + kc * 512), accv0);
        accv1 = mfma_bf16(a, *(const bhalf8*)(wv1 + kc * 512), accv1);
    }

    // ---- K epilogue (verbatim) ----
    {
        f32x4 accs[2] = {acck0, acck1};
        #pragma unroll
        for (int nt = 0; nt < 2; nt++) {
            int col = col0 + nt * 16 + l16;
            float bs = bk[col];
            int hh = col >> 6, dim = col & 63;
            int f = dim >> 5, q8 = (dim >> 3) & 3, i8 = dim & 7;
            #pragma unroll
            for (int r = 0; r < 4; r++) {
                int row = row0 + quad * 4 + r;
                int bb = row / Skv; int key = row - bb * Skv;
                size_t off = (size_t)(bb * 4 + hh) * Skv * 64 + (size_t)(key >> 4) * 1024
                           + f * 512 + q8 * 128 + (key & 15) * 8 + i8;
                kout[off] = f2bf(accs[nt][r] + bs);
            }
        }
    }
    // ---- V epilogue (verbatim) ----
    {
        f32x4 accs[2] = {accv0, accv1};
        #pragma unroll
        for (int nt = 0; nt < 2; nt++) {
            int col = col0 + nt * 16 + l16;
            float bs = bv[col];
            int hh = col >> 6, dim = col & 63;
            int ntg = dim >> 4, l16v = dim & 15;
            int row = row0 + quad * 4;
            int bb = row / Skv; int key = row - bb * Skv;
            size_t off = (size_t)(bb * 4 + hh) * Skv * 64 + (size_t)(key >> 4) * 1024
                       + ntg * 256 + ((key & 15) >> 2) * 64 + l16v * 4;
            ushort4 pk;
            pk.x = f2bf(accs[nt][0] + bs);
            pk.y = f2bf(accs[nt][1] + bs);
            pk.z = f2bf(accs[nt][2] + bs);
            pk.w = f2bf(accs[nt][3] + bs);
            *(ushort4*)(vout + off) = pk;
        }
    }
}

// ---------------- QKV GEMM (all operands fragment-major) ----------------
__global__ __launch_bounds__(256) void k_gemm_qkv(const u16* A0, const u16* A2,
                                                  const u16* Wfm0, const float* bias0,
                                                  u16* qout, u16* kfm_out, u16* vfm_out,
                                                  int K, long wz, long bz, float scale0,
                                                  int kz, int vz, int Skv, int M0) {
    int z = blockIdx.z;
    int wave = threadIdx.x >> 6, lane = threadIdx.x & 63;
    int l16 = lane & 15, quad = lane >> 4;
    int row0 = blockIdx.x * 64 + wave * 16;
    int col0 = blockIdx.y * 32;
    const u16* A;
    if (z == 0) { if (row0 >= M0) return; A = A0; } else { A = A2; }
    const u16* Wfm = Wfm0 + (size_t)z * wz;
    const float* bias = bias0 + (size_t)z * bz;
    int Kc = K >> 5;

    f32x4 acc0 = (f32x4){0.f, 0.f, 0.f, 0.f};
    f32x4 acc1 = (f32x4){0.f, 0.f, 0.f, 0.f};
    const u16* ab = A + (size_t)(row0 >> 4) * Kc * 512 + lane * 8;
    const u16* wb0 = Wfm + (size_t)(col0 >> 4) * Kc * 512 + lane * 8;
    const u16* wb1 = wb0 + (size_t)Kc * 512;
    #pragma unroll 4
    for (int kc = 0; kc < Kc; kc++) {
        bhalf8 a = *(const bhalf8*)(ab + kc * 512);
        acc0 = mfma_bf16(a, *(const bhalf8*)(wb0 + kc * 512), acc0);
        acc1 = mfma_bf16(a, *(const bhalf8*)(wb1 + kc * 512), acc1);
    }

    f32x4 accs[2] = {acc0, acc1};
    #pragma unroll
    for (int nt = 0; nt < 2; nt++) {
        int col = col0 + nt * 16 + l16;
        float bs = bias[col];
        if (z == kz) {
            int hh = col >> 6, dim = col & 63;
            int f = dim >> 5, q8 = (dim >> 3) & 3, i8 = dim & 7;
            #pragma unroll
            for (int r = 0; r < 4; r++) {
                int row = row0 + quad * 4 + r;
                int bb = row / Skv; int key = row - bb * Skv;
                size_t off = (size_t)(bb * 4 + hh) * Skv * 64 + (size_t)(key >> 4) * 1024
                           + f * 512 + q8 * 128 + (key & 15) * 8 + i8;
                kfm_out[off] = f2bf(accs[nt][r] + bs);
            }
        } else if (z == vz) {
            int hh = col >> 6, dim = col & 63;
            int ntg = dim >> 4, l16v = dim & 15;
            int row = row0 + quad * 4;
            int bb = row / Skv; int key = row - bb * Skv;
            size_t off = (size_t)(bb * 4 + hh) * Skv * 64 + (size_t)(key >> 4) * 1024
                       + ntg * 256 + ((key & 15) >> 2) * 64 + l16v * 4;
            ushort4 pk;
            pk.x = f2bf(accs[nt][0] + bs);
            pk.y = f2bf(accs[nt][1] + bs);
            pk.z = f2bf(accs[nt][2] + bs);
            pk.w = f2bf(accs[nt][3] + bs);
            *(ushort4*)(vfm_out + off) = pk;
        } else {
            size_t base = ((size_t)(row0 >> 4) * 8 + blockIdx.y) * 512;
            int g3 = (nt * 2 + (l16 >> 3)) & 3;
            int i = l16 & 7;
            #pragma unroll
            for (int r = 0; r < 4; r++)
                qout[base + (((quad * 4 + r) + 16 * g3) << 3) + i] =
                    f2bf((accs[nt][r] + bs) * scale0);
        }
    }
}

// ---------------- GEMM + bias + residual + LayerNorm (8 waves) ----------------
__global__ __launch_bounds__(512) void k_gemm_ln(const u16* A, const u16* Wfm, const float* bias,
                                                 const float* res, const float* g, const float* beta,
                                                 float* outf, u16* outb, int K) {
    int t = threadIdx.x;
    int w = t >> 6, lane = t & 63;
    int l16 = lane & 15, quad = lane >> 4;
    int row0 = blockIdx.x * 16;
    int Kc = K >> 5;

    f32x4 acc[2];
    acc[0] = (f32x4){0.f, 0.f, 0.f, 0.f};
    acc[1] = (f32x4){0.f, 0.f, 0.f, 0.f};

    const u16* ab = A + (size_t)blockIdx.x * Kc * 512 + lane * 8;
    const u16* wb = Wfm + (size_t)(w * 2) * Kc * 512 + lane * 8;
    #pragma unroll 4
    for (int kc = 0; kc < Kc; kc++) {
        bhalf8 a = *(const bhalf8*)(ab + kc * 512);
        acc[0] = mfma_bf16(a, *(const bhalf8*)(wb + kc * 512), acc[0]);
        acc[1] = mfma_bf16(a, *(const bhalf8*)(wb + (size_t)(Kc + kc) * 512), acc[1]);
    }

    float sr[4] = {0.f, 0.f, 0.f, 0.f}, s2r[4] = {0.f, 0.f, 0.f, 0.f};
    #pragma unroll
    for (int nt = 0; nt < 2; nt++) {
        int col = w * 32 + nt * 16 + l16;
        float bs = bias[col];
        #pragma unroll
        for (int r = 0; r < 4; r++) {
            int row = row0 + quad * 4 + r;
            float v = acc[nt][r] + bs + res[(size_t)row * 256 + col];
            acc[nt][r] = v;
            sr[r] += v; s2r[r] += v * v;
        }
    }
    #pragma unroll
    for (int r = 0; r < 4; r++) {
        #pragma unroll
        for (int off = 8; off >= 1; off >>= 1) {
            sr[r]  += __shfl_xor(sr[r], off, 16);
            s2r[r] += __shfl_xor(s2r[r], off, 16);
        }
    }
    __shared__ float lsm[8][16], lsq[8][16];
    if (l16 == 0) {
        #pragma unroll
        for (int r = 0; r < 4; r++) { lsm[w][quad * 4 + r] = sr[r]; lsq[w][quad * 4 + r] = s2r[r]; }
    }
    __syncthreads();
    float mu[4], rs[4];
    #pragma unroll
    for (int r = 0; r < 4; r++) {
        int ri = quad * 4 + r;
        float ts = 0.f, tq = 0.f;
        #pragma unroll
        for (int ww = 0; ww < 8; ww++) { ts += lsm[ww][ri]; tq += lsq[ww][ri]; }
        mu[r] = ts * (1.f / 256.f);
        float var = tq * (1.f / 256.f) - mu[r] * mu[r];
        rs[r] = rsqrtf(var + 1e-12f);
    }
    size_t base = ((size_t)blockIdx.x * 8 + w) * 512;
    #pragma unroll
    for (int nt = 0; nt < 2; nt++) {
        int col = w * 32 + nt * 16 + l16;
        float gc = g[col], bc = beta[col];
        int g3 = (nt * 2 + (l16 >> 3)) & 3;
        int i = l16 & 7;
        #pragma unroll
        for (int r = 0; r < 4; r++) {
            int row = row0 + quad * 4 + r;
            float yv = (acc[nt][r] - mu[r]) * rs[r] * gc + bc;
            outf[(size_t)row * 256 + col] = yv;
            outb[base + (((quad * 4 + r) + 16 * g3) << 3) + i] = f2bf(yv);
        }
    }
}

// ---------------- fused FFN: GEMM1+GELU -> LDS -> GEMM2 + res + LN -----------
// Round-11 change (weight-BW): 32 rows/block (128 blocks). Each W1/W2 fragment
// load feeds BOTH 16-row tiles -> weight traffic 268 -> ~137 MB per launch.
// f1 LDS 64 KB (2 x 32 chunks), 2 blocks/CU; per-row accumulation order
// unchanged -> bit-identical output. VGPR peak ~85 (acc[2][8] in stage 1).
__global__ __launch_bounds__(512, 4) void k_ffn(const u16* A, const u16* W1, const float* b1,
                                                const u16* W2, const float* b2,
                                                const float* res, const float* g, const float* beta,
                                                float* outf, u16* outb) {
    int t = threadIdx.x;
    int w = t >> 6, lane = t & 63;
    int l16 = lane & 15, quad = lane >> 4;
    int row0 = blockIdx.x * 32;

    __shared__ u16 f1lds[2 * 32 * 512];    // 64 KB: [rt][32 chunks][512]
    __shared__ float lsm[2][8][16], lsq[2][8][16];

    // ---- stage 1: f1 = A @ W1 (K=256, Kc=8), wave w -> 8 n-tiles x 2 row-tiles ----
    f32x4 acc[2][8];
    #pragma unroll
    for (int rt = 0; rt < 2; rt++)
        #pragma unroll
        for (int nt = 0; nt < 8; nt++) acc[rt][nt] = (f32x4){0.f, 0.f, 0.f, 0.f};
    const u16* ab0 = A + ((size_t)blockIdx.x * 2) * 8 * 512 + lane * 8;
    const u16* ab1 = ab0 + 8 * 512;
    const u16* w1b = W1 + (size_t)(w * 8) * 8 * 512 + lane * 8;
    #pragma unroll
    for (int kc = 0; kc < 8; kc++) {
        bhalf8 a0 = *(const bhalf8*)(ab0 + kc * 512);
        bhalf8 a1 = *(const bhalf8*)(ab1 + kc * 512);
        #pragma unroll
        for (int nt = 0; nt < 8; nt++) {
            bhalf8 wf = *(const bhalf8*)(w1b + ((size_t)nt * 8 + kc) * 512);
            acc[0][nt] = mfma_bf16(a0, wf, acc[0][nt]);
            acc[1][nt] = mfma_bf16(a1, wf, acc[1][nt]);
        }
    }
    // GELU + pack to LDS afm (per row-tile)
    #pragma unroll
    for (int rt = 0; rt < 2; rt++)
    #pragma unroll
    for (int nt = 0; nt < 8; nt++) {
        int col = w * 128 + nt * 16 + l16;
        float bs = b1[col];
        int chunk = w * 4 + (nt >> 1);
        int g3 = (nt * 2 + (l16 >> 3)) & 3;
        int i = l16 & 7;
        #pragma unroll
        for (int r = 0; r < 4; r++) {
            float v = acc[rt][nt][r] + bs;
            float ge = 0.5f * v * (1.f + tanhf(0.7978845608028654f * (v + 0.044715f * v * v * v)));
            f1lds[rt * 16384 + chunk * 512 + (((quad * 4 + r) + 16 * g3) << 3) + i] = f2bf(ge);
        }
    }
    __syncthreads();

    // ---- stage 2: out = f1 @ W2 (K=1024, Kc=32), wave w -> 2 n-tiles x 2 row-tiles
    // each W2 fragment loaded ONCE for both row-tiles ----
    f32x4 acc2[2][2];
    #pragma unroll
    for (int rt = 0; rt < 2; rt++) {
        acc2[rt][0] = (f32x4){0.f, 0.f, 0.f, 0.f};
        acc2[rt][1] = (f32x4){0.f, 0.f, 0.f, 0.f};
    }
    const u16* w2b = W2 + (size_t)(w * 2) * 32 * 512 + lane * 8;
    #pragma unroll 4
    for (int kc = 0; kc < 32; kc++) {
        bhalf8 wf0 = *(const bhalf8*)(w2b + (size_t)kc * 512);
        bhalf8 wf1 = *(const bhalf8*)(w2b + (size_t)(32 + kc) * 512);
        bhalf8 af0 = *(const bhalf8*)&f1lds[kc * 512 + lane * 8];
        bhalf8 af1 = *(const bhalf8*)&f1lds[16384 + kc * 512 + lane * 8];
        acc2[0][0] = mfma_bf16(af0, wf0, acc2[0][0]);
        acc2[0][1] = mfma_bf16(af0, wf1, acc2[0][1]);
        acc2[1][0] = mfma_bf16(af1, wf0, acc2[1][0]);
        acc2[1][1] = mfma_bf16(af1, wf1, acc2[1][1]);
    }

    // ---- stage 3: bias + residual + LN (per row-tile) ----
    float sr[2][4], s2r[2][4];
    #pragma unroll
    for (int rt = 0; rt < 2; rt++)
        #pragma unroll
        for (int r = 0; r < 4; r++) { sr[rt][r] = 0.f; s2r[rt][r] = 0.f; }
    #pragma unroll
    for (int rt = 0; rt < 2; rt++)
    #pragma unroll
    for (int nt = 0; nt < 2; nt++) {
        int col = w * 32 + nt * 16 + l16;
        float bs = b2[col];
        #pragma unroll
        for (int r = 0; r < 4; r++) {
            int row = row0 + rt * 16 + quad * 4 + r;
            float v = acc2[rt][nt][r] + bs + res[(size_t)row * 256 + col];
            acc2[rt][nt][r] = v;
            sr[rt][r] += v; s2r[rt][r] += v * v;
        }
    }
    #pragma unroll
    for (int rt = 0; rt < 2; rt++)
    #pragma unroll
    for (int r = 0; r < 4; r++) {
        #pragma unroll
        for (int off = 8; off >= 1; off >>= 1) {
            sr[rt][r]  += __shfl_xor(sr[rt][r], off, 16);
            s2r[rt][r] += __shfl_xor(s2r[rt][r], off, 16);
        }
    }
    if (l16 == 0) {
        #pragma unroll
        for (int rt = 0; rt < 2; rt++)
        #pragma unroll
        for (int r = 0; r < 4; r++) {
            lsm[rt][w][quad * 4 + r] = sr[rt][r];
            lsq[rt][w][quad * 4 + r] = s2r[rt][r];
        }
    }
    __syncthreads();
    #pragma unroll
    for (int rt = 0; rt < 2; rt++) {
        float mu[4], rs[4];
        #pragma unroll
        for (int r = 0; r < 4; r++) {
            int ri = quad * 4 + r;
            float ts = 0.f, tq = 0.f;
            #pragma unroll
            for (int ww = 0; ww < 8; ww++) { ts += lsm[rt][ww][ri]; tq += lsq[rt][ww][ri]; }
            mu[r] = ts * (1.f / 256.f);
            float var = tq * (1.f / 256.f) - mu[r] * mu[r];
            rs[r] = rsqrtf(var + 1e-12f);
        }
        size_t base = (((size_t)blockIdx.x * 2 + rt) * 8 + w) * 512;
        #pragma unroll
        for (int nt = 0; nt < 2; nt++) {
            int col = w * 32 + nt * 16 + l16;
            float gc = g[col], bc = beta[col];
            int g3 = (nt * 2 + (l16 >> 3)) & 3;
            int i = l16 & 7;
            #pragma unroll
            for (int r = 0; r < 4; r++) {
                int row = row0 + rt * 16 + quad * 4 + r;
                float yv = (acc2[rt][nt][r] - mu[r]) * rs[r] * gc + bc;
                outf[(size_t)row * 256 + col] = yv;
                outb[base + (((quad * 4 + r) + 16 * g3) << 3) + i] = f2bf(yv);
            }
        }
    }
}

// ---------------- flash attention (fragment-major Q/K/V, afm ctx out) ----------
// Verified round-8 structure (863.7µs total): 512 thr = 8 waves, TWO 16-row
// q-tiles, 8-way key split, pk2bf inner loop, unroll 2, wave0-serial combine.
// SETTLED — do not touch. (Round-10 q-major rewrite: 6.6x regression from
// 1-block/CU latency starvation; key-split + deep TLP is the right design.)
__global__ __launch_bounds__(512, 4) void k_attn(const u16* q, const u16* kfm, const u16* vfm,
                                                 u16* ctx, int Sq, int Sk) {
    int bh = blockIdx.x & 7;
    int b = bh >> 2, h = bh & 3;
    int qp = blockIdx.x >> 3;
    int t = threadIdx.x;
    int kw = t >> 6, lane = t & 63;     // kw in [0,8)
    int l16 = lane & 15, quad = lane >> 4;
    int q0 = qp * 32;                   // rows q0 .. q0+31 (two 16-row tiles)

    // stride 20 floats: bank = quad*16 + l16 (mod 32) -> 2-way (free)
    __shared__ float opart[2][7][64][20];
    __shared__ float lsum[2][7][16];

    size_t rt0 = (size_t)((b * Sq + q0) >> 4);
    const u16* qb = q + (rt0 * 8 + h * 2) * 512 + lane * 8;
    bhalf8 bq00 = *(const bhalf8*)(qb);
    bhalf8 bq01 = *(const bhalf8*)(qb + 512);
    bhalf8 bq10 = *(const bhalf8*)(qb + 8 * 512);   // next q-tile: +8 chunks
    bhalf8 bq11 = *(const bhalf8*)(qb + 9 * 512);

    const u16* kwb = kfm + (size_t)(b * 4 + h) * Sk * 64;
    const u16* vwb = vfm + (size_t)(b * 4 + h) * Sk * 64;

    int nT = Sk >> 7;          // 16-key tiles per wave (8-way split)
    int T0 = kw * nT;

    float l0 = 0.f, l1 = 0.f;
    f32x4 o0[4], o1[4];
    #pragma unroll
    for (int nt = 0; nt < 4; nt++) {
        o0[nt] = (f32x4){0.f, 0.f, 0.f, 0.f};
        o1[nt] = (f32x4){0.f, 0.f, 0.f, 0.f};
    }

    #pragma unroll 2
    for (int T = T0; T < T0 + nT; T++) {
        const u16* kt = kwb + (size_t)T * 1024;
        bhalf8 a0 = *(const bhalf8*)(kt + lane * 8);
        bhalf8 a1 = *(const bhalf8*)(kt + 512 + lane * 8);
        f32x4 s0 = (f32x4){0.f, 0.f, 0.f, 0.f};
        f32x4 s1 = (f32x4){0.f, 0.f, 0.f, 0.f};
        s0 = mfma_bf16(a0, bq00, s0);
        s0 = mfma_bf16(a1, bq01, s0);
        s1 = mfma_bf16(a0, bq10, s1);
        s1 = mfma_bf16(a1, bq11, s1);

        float p0[4], p1[4], ps0 = 0.f, ps1 = 0.f;
        #pragma unroll
        for (int r = 0; r < 4; r++) {
            p0[r] = exp2f(s0[r] - 11.5415603f);
            ps0 += p0[r];
            p1[r] = exp2f(s1[r] - 11.5415603f);
            ps1 += p1[r];
        }
        l0 += ps0; l1 += ps1;

        union { bhalf4 v; unsigned u[2]; } bp0, bp1;
        bp0.u[0] = pk2bf(p0[0], p0[1]);
        bp0.u[1] = pk2bf(p0[2], p0[3]);
        bp1.u[0] = pk2bf(p1[0], p1[1]);
        bp1.u[1] = pk2bf(p1[2], p1[3]);

        const u16* vts = vwb + (size_t)T * 1024 + quad * 64 + l16 * 4;
        #pragma unroll
        for (int nt = 0; nt < 4; nt++) {
            bhalf4 va = *(const bhalf4*)(vts + nt * 256);
            o0[nt] = mfma16_bf16(va, bp0.v, o0[nt]);
            o1[nt] = mfma16_bf16(va, bp1.v, o1[nt]);
        }
    }

    float lc0 = l0, lc1 = l1;
    lc0 += __shfl_xor(lc0, 16, 64);
    lc0 += __shfl_xor(lc0, 32, 64);
    lc1 += __shfl_xor(lc1, 16, 64);
    lc1 += __shfl_xor(lc1, 32, 64);

    if (kw > 0) {
        #pragma unroll
        for (int nt = 0; nt < 4; nt++)
            #pragma unroll
            for (int r = 0; r < 4; r++) {
                opart[0][kw - 1][nt * 16 + quad * 4 + r][l16] = o0[nt][r];
                opart[1][kw - 1][nt * 16 + quad * 4 + r][l16] = o1[nt][r];
            }
        if (quad == 0) {
            lsum[0][kw - 1][l16] = lc0;
            lsum[1][kw - 1][l16] = lc1;
        }
    }
    __syncthreads();
    if (kw == 0) {
        float L0 = lc0, L1 = lc1;
        #pragma unroll
        for (int ww = 0; ww < 7; ww++) {
            L0 += lsum[0][ww][l16];
            L1 += lsum[1][ww][l16];
        }
        float invL0 = 1.f / L0;
        float invL1 = 1.f / L1;
        #pragma unroll
        for (int nt = 0; nt < 4; nt++) {
            ushort4 pkv0, pkv1;
            #pragma unroll
            for (int r = 0; r < 4; r++) {
                float v0 = o0[nt][r];
                float v1 = o1[nt][r];
                #pragma unroll
                for (int ww = 0; ww < 7; ww++) {
                    v0 += opart[0][ww][nt * 16 + quad * 4 + r][l16];
                    v1 += opart[1][ww][nt * 16 + quad * 4 + r][l16];
                }
                ((u16*)&pkv0)[r] = f2bf(v0 * invL0);
                ((u16*)&pkv1)[r] = f2bf(v1 * invL1);
            }
            size_t ce = ((l16 + 16 * ((nt * 2 + (quad >> 1)) & 3)) << 3) + (quad & 1) * 4;
            size_t off0 = (rt0 * 8 + (h * 2 + (nt >> 1))) * 512 + ce;
            size_t off1 = ((rt0 + 1) * 8 + (h * 2 + (nt >> 1))) * 512 + ce;
            *(ushort4*)(ctx + off0) = pkv0;
            *(ushort4*)(ctx + off1) = pkv1;
        }
    }
}

// ---------------- host ----------------
extern "C" void kernel_launch(void* const* d_in, const int* in_sizes, int n_in,
                              void* d_out, int out_size, void* d_ws, size_t ws_size,
                              hipStream_t stream) {
    const float* x        = (const float*)d_in[0];
    const float* y        = (const float*)d_in[1];
    const float* pos      = (const float*)d_in[2];
    const float* sqkv_w   = (const float*)d_in[3];
    const float* sqkv_b   = (const float*)d_in[4];
    const float* so_w     = (const float*)d_in[5];
    const float* so_b     = (const float*)d_in[6];
    const float* cqkv_w   = (const float*)d_in[7];
    const float* cqkv_b   = (const float*)d_in[8];
    const float* co_w     = (const float*)d_in[9];
    const float* co_b     = (const float*)d_in[10];
    const float* ffn_w1   = (const float*)d_in[11];
    const float* ffn_b1   = (const float*)d_in[12];
    const float* ffn_w2   = (const float*)d_in[13];
    const float* ffn_b2   = (const float*)d_in[14];
    const float* ln_g     = (const float*)d_in[15];
    const float* ln_b     = (const float*)d_in[16];

    char* w = (char*)d_ws;
    auto alloc = [&](size_t bytes) { char* p = w; w += (bytes + 255) & ~(size_t)255; return p; };

    u16* wt_sqkv = (u16*)alloc(18ull * 65536 * 2);
    u16* wt_so   = (u16*)alloc(6ull  * 65536 * 2);
    u16* wt_cqkv = (u16*)alloc(18ull * 65536 * 2);
    u16* wt_co   = (u16*)alloc(6ull  * 65536 * 2);
    u16* wt_f1   = (u16*)alloc(6ull  * 262144 * 2);
    u16* wt_f2   = (u16*)alloc(6ull  * 262144 * 2);
    u16* xp      = (u16*)alloc(2097152ull * 2);
    float* hf    = (float*)alloc(1048576ull * 4);
    u16* hb      = (u16*)alloc(1048576ull * 2);
    u16* qbuf    = (u16*)alloc(1048576ull * 2);
    u16* kfm     = (u16*)alloc(2097152ull * 2);
    u16* vfm     = (u16*)alloc(2097152ull * 2);
    u16* ctx     = (u16*)alloc(1048576ull * 2);
    u16* kfm_all = (u16*)alloc(6ull * 2097152 * 2);   // per-layer cross K (24 MB)
    u16* vfm_all = (u16*)alloc(6ull * 2097152 * 2);   // per-layer cross V (24 MB)

    k_wtrans_fm<<<dim3(256, 18), 256, 0, stream>>>(sqkv_w, wt_sqkv, 256, 256);
    k_wtrans_fm<<<dim3(256, 6),  256, 0, stream>>>(so_w,   wt_so,   256, 256);
    k_wtrans_fm<<<dim3(256, 18), 256, 0, stream>>>(cqkv_w, wt_cqkv, 256, 256);
    k_wtrans_fm<<<dim3(256, 6),  256, 0, stream>>>(co_w,   wt_co,   256, 256);
    k_wtrans_fm<<<dim3(1024, 6), 256, 0, stream>>>(ffn_w1, wt_f1,   256, 1024);
    k_wtrans_fm<<<dim3(1024, 6), 256, 0, stream>>>(ffn_w2, wt_f2,   1024, 256);
    k_addpos<<<dim3(8192), 256, 0, stream>>>(x, pos, xp);
    k_inith<<<dim3(4096), 256, 0, stream>>>(y, hf, hb);
    // cross K/V for all 6 layers: layer-invariant A=xp, fused K+V per block
    k_kv_pre<<<dim3(128, 8, 6), 256, 0, stream>>>(xp, wt_cqkv, cqkv_b, kfm_all, vfm_all);

    const float qscale = 0.125f * 1.44269504f;  // 1/sqrt(64) * log2(e)

    for (int i = 0; i < 6; i++) {
        // ---- self attention ----
        k_gemm_qkv<<<dim3(64, 8, 3), 256, 0, stream>>>(hb, hb,
            wt_sqkv + (size_t)i * 3 * 65536, sqkv_b + i * 768,
            qbuf, kfm, vfm, 256, 65536, 256, qscale, 1, 2, 2048, 4096);
        k_attn<<<dim3(512), 512, 0, stream>>>(qbuf, kfm, vfm, ctx, 2048, 2048);
        k_gemm_ln<<<dim3(256), 512, 0, stream>>>(ctx, wt_so + (size_t)i * 65536,
            so_b + i * 256, hf, ln_g + (i * 3 + 0) * 256, ln_b + (i * 3 + 0) * 256,
            hf, hb, 256);

        // ---- cross attention (K/V precomputed; only q GEMM in-loop) ----
        k_gemm_qkv<<<dim3(64, 8, 1), 256, 0, stream>>>(hb, xp,
            wt_cqkv + (size_t)i * 3 * 65536, cqkv_b + i * 768,
            qbuf, kfm, vfm, 256, 65536, 256, qscale, 1, 2, 4096, 4096);
        k_attn<<<dim3(512), 512, 0, stream>>>(qbuf,
            kfm_all + (size_t)i * 2097152, vfm_all + (size_t)i * 2097152, ctx, 2048, 4096);
        k_gemm_ln<<<dim3(256), 512, 0, stream>>>(ctx, wt_co + (size_t)i * 65536,
            co_b + i * 256, hf, ln_g + (i * 3 + 1) * 256, ln_b + (i * 3 + 1) * 256,
            hf, hb, 256);

        // ---- fused FFN (32 rows/block, weight traffic halved) ----
        float* dst = (i == 5) ? (float*)d_out : hf;
        k_ffn<<<dim3(128), 512, 0, stream>>>(hb, wt_f1 + (size_t)i * 262144,
            ffn_b1 + i * 1024, wt_f2 + (size_t)i * 262144, ffn_b2 + i * 256,
            hf, ln_g + (i * 3 + 2) * 256, ln_b + (i * 3 + 2) * 256, dst, hb);
    }
}

// Round 12
// 883.750 us; speedup vs baseline: 3.2553x; 1.0244x over previous
//
#include <hip/hip_runtime.h>
#include <hip/hip_bf16.h>

typedef unsigned short u16;
typedef __attribute__((ext_vector_type(8))) short bhalf8;
typedef __attribute__((ext_vector_type(4))) short bhalf4;
typedef __attribute__((ext_vector_type(4))) float f32x4;

__device__ inline f32x4 mfma_bf16(bhalf8 a, bhalf8 b, f32x4 c) {
    return __builtin_amdgcn_mfma_f32_16x16x32_bf16(a, b, c, 0, 0, 0);
}
__device__ inline f32x4 mfma16_bf16(bhalf4 a, bhalf4 b, f32x4 c) {
    return __builtin_amdgcn_mfma_f32_16x16x16bf16_1k(a, b, c, 0, 0, 0);
}

__device__ inline u16 f2bf(float f) {
    union { float f; unsigned u; } v; v.f = f;
    unsigned u = v.u;
    return (u16)((u + 0x7fff + ((u >> 16) & 1)) >> 16);
}
// native packed f32x2 -> bf16x2 (RNE; identical rounding to f2bf on finite vals)
__device__ inline unsigned pk2bf(float lo, float hi) {
    union { __hip_bfloat162 h; unsigned u; } v;
    v.h = __float22bfloat162_rn(float2{lo, hi});
    return v.u;
}

// Fragment-major (afm) layout for [M][C] bf16: tile t=row>>4, chunk kc=col>>5,
// lane' = (row&15) + 16*((col>>3)&3), elem i = col&7.
__device__ inline size_t afm_off(int row, int col, int Cc) {
    return ((size_t)((row >> 4) * Cc + (col >> 5))) * 512
         + (((row & 15) + 16 * ((col >> 3) & 3)) << 3) + (col & 7);
}

// ---------------- prologue kernels ----------------

__global__ __launch_bounds__(256) void k_wtrans_fm(const float* in, u16* out, int rows, int cols) {
    int mat = blockIdx.y;
    size_t rc = (size_t)rows * cols;
    size_t idx = (size_t)blockIdx.x * 256 + threadIdx.x;
    if (idx >= rc) return;
    int r = (int)(idx / cols), c = (int)(idx % cols);   // r=k, c=n
    size_t off = ((size_t)((c >> 4) * (rows >> 5) + (r >> 5))) * 512
               + (((c & 15) + 16 * ((r >> 3) & 3)) << 3) + (r & 7);
    out[mat * rc + off] = f2bf(in[mat * rc + idx]);
}

__global__ __launch_bounds__(256) void k_addpos(const float* x, const float* pos, u16* xp) {
    size_t idx = (size_t)blockIdx.x * 256 + threadIdx.x;
    size_t p = idx & ((size_t)4096 * 256 - 1);
    int row = (int)(idx >> 8), col = (int)(idx & 255);
    xp[afm_off(row, col, 8)] = f2bf(x[idx] + pos[p]);
}

__global__ __launch_bounds__(256) void k_inith(const float* y, float* h, u16* hb) {
    size_t idx = (size_t)blockIdx.x * 256 + threadIdx.x;
    float v = y[idx];
    h[idx] = v;
    int row = (int)(idx >> 8), col = (int)(idx & 255);
    hb[afm_off(row, col, 8)] = f2bf(v);
}

// ---------------- precompute cross K/V for ALL layers (layer-invariant A=xp) ----
// Round-12: register-level reuse extended (round-8 pattern that gave 48.5->43.8).
// Grid (128,4,6) = 3072 blocks (12/CU); each block covers 64 rows x 64 cols via
// 2 col-pairs: 8 accumulators, each A-fragment load feeds 8 MFMAs. Traffic
// 384 -> 192 MB. NO LDS staging (round-9 failure mode avoided). Per-output kc
// order unchanged -> bit-identical.
__global__ __launch_bounds__(256) void k_kv_pre(const u16* A2, const u16* Wall, const float* ball,
                                                u16* kfm_all, u16* vfm_all) {
    const int Skv = 4096;
    int layer = blockIdx.z;
    int wave = threadIdx.x >> 6, lane = threadIdx.x & 63;
    int l16 = lane & 15, quad = lane >> 4;
    int row0 = blockIdx.x * 64 + wave * 16;
    const u16* Wk = Wall + (size_t)layer * 3 * 65536 + 65536;
    const u16* Wv = Wk + 65536;
    const float* bk = ball + layer * 768 + 256;
    const float* bv = bk + 256;
    u16* kout = kfm_all + (size_t)layer * 2097152;
    u16* vout = vfm_all + (size_t)layer * 2097152;
    const int Kc = 8;

    f32x4 acck[2][2], accv[2][2];
    #pragma unroll
    for (int cp = 0; cp < 2; cp++)
        #pragma unroll
        for (int nt = 0; nt < 2; nt++) {
            acck[cp][nt] = (f32x4){0.f, 0.f, 0.f, 0.f};
            accv[cp][nt] = (f32x4){0.f, 0.f, 0.f, 0.f};
        }
    const u16* ab = A2 + (size_t)(row0 >> 4) * Kc * 512 + lane * 8;
    const u16* wkb = Wk + (size_t)(blockIdx.y * 4) * Kc * 512 + lane * 8;
    const u16* wvb = Wv + (size_t)(blockIdx.y * 4) * Kc * 512 + lane * 8;
    #pragma unroll
    for (int kc = 0; kc < Kc; kc++) {
        bhalf8 a = *(const bhalf8*)(ab + kc * 512);
        #pragma unroll
        for (int cp = 0; cp < 2; cp++)
            #pragma unroll
            for (int nt = 0; nt < 2; nt++) {
                size_t wt = (size_t)(cp * 2 + nt) * Kc * 512 + kc * 512;
                acck[cp][nt] = mfma_bf16(a, *(const bhalf8*)(wkb + wt), acck[cp][nt]);
                accv[cp][nt] = mfma_bf16(a, *(const bhalf8*)(wvb + wt), accv[cp][nt]);
            }
    }

    #pragma unroll
    for (int cp = 0; cp < 2; cp++) {
        int col0 = blockIdx.y * 64 + cp * 32;
        // ---- K epilogue (verbatim) ----
        {
            f32x4 accs[2] = {acck[cp][0], acck[cp][1]};
            #pragma unroll
            for (int nt = 0; nt < 2; nt++) {
                int col = col0 + nt * 16 + l16;
                float bs = bk[col];
                int hh = col >> 6, dim = col & 63;
                int f = dim >> 5, q8 = (dim >> 3) & 3, i8 = dim & 7;
                #pragma unroll
                for (int r = 0; r < 4; r++) {
                    int row = row0 + quad * 4 + r;
                    int bb = row / Skv; int key = row - bb * Skv;
                    size_t off = (size_t)(bb * 4 + hh) * Skv * 64 + (size_t)(key >> 4) * 1024
                               + f * 512 + q8 * 128 + (key & 15) * 8 + i8;
                    kout[off] = f2bf(accs[nt][r] + bs);
                }
            }
        }
        // ---- V epilogue (verbatim) ----
        {
            f32x4 accs[2] = {accv[cp][0], accv[cp][1]};
            #pragma unroll
            for (int nt = 0; nt < 2; nt++) {
                int col = col0 + nt * 16 + l16;
                float bs = bv[col];
                int hh = col >> 6, dim = col & 63;
                int ntg = dim >> 4, l16v = dim & 15;
                int row = row0 + quad * 4;
                int bb = row / Skv; int key = row - bb * Skv;
                size_t off = (size_t)(bb * 4 + hh) * Skv * 64 + (size_t)(key >> 4) * 1024
                           + ntg * 256 + ((key & 15) >> 2) * 64 + l16v * 4;
                ushort4 pk;
                pk.x = f2bf(accs[nt][0] + bs);
                pk.y = f2bf(accs[nt][1] + bs);
                pk.z = f2bf(accs[nt][2] + bs);
                pk.w = f2bf(accs[nt][3] + bs);
                *(ushort4*)(vout + off) = pk;
            }
        }
    }
}

// ---------------- QKV GEMM (all operands fragment-major) ----------------
__global__ __launch_bounds__(256) void k_gemm_qkv(const u16* A0, const u16* A2,
                                                  const u16* Wfm0, const float* bias0,
                                                  u16* qout, u16* kfm_out, u16* vfm_out,
                                                  int K, long wz, long bz, float scale0,
                                                  int kz, int vz, int Skv, int M0) {
    int z = blockIdx.z;
    int wave = threadIdx.x >> 6, lane = threadIdx.x & 63;
    int l16 = lane & 15, quad = lane >> 4;
    int row0 = blockIdx.x * 64 + wave * 16;
    int col0 = blockIdx.y * 32;
    const u16* A;
    if (z == 0) { if (row0 >= M0) return; A = A0; } else { A = A2; }
    const u16* Wfm = Wfm0 + (size_t)z * wz;
    const float* bias = bias0 + (size_t)z * bz;
    int Kc = K >> 5;

    f32x4 acc0 = (f32x4){0.f, 0.f, 0.f, 0.f};
    f32x4 acc1 = (f32x4){0.f, 0.f, 0.f, 0.f};
    const u16* ab = A + (size_t)(row0 >> 4) * Kc * 512 + lane * 8;
    const u16* wb0 = Wfm + (size_t)(col0 >> 4) * Kc * 512 + lane * 8;
    const u16* wb1 = wb0 + (size_t)Kc * 512;
    #pragma unroll 4
    for (int kc = 0; kc < Kc; kc++) {
        bhalf8 a = *(const bhalf8*)(ab + kc * 512);
        acc0 = mfma_bf16(a, *(const bhalf8*)(wb0 + kc * 512), acc0);
        acc1 = mfma_bf16(a, *(const bhalf8*)(wb1 + kc * 512), acc1);
    }

    f32x4 accs[2] = {acc0, acc1};
    #pragma unroll
    for (int nt = 0; nt < 2; nt++) {
        int col = col0 + nt * 16 + l16;
        float bs = bias[col];
        if (z == kz) {
            int hh = col >> 6, dim = col & 63;
            int f = dim >> 5, q8 = (dim >> 3) & 3, i8 = dim & 7;
            #pragma unroll
            for (int r = 0; r < 4; r++) {
                int row = row0 + quad * 4 + r;
                int bb = row / Skv; int key = row - bb * Skv;
                size_t off = (size_t)(bb * 4 + hh) * Skv * 64 + (size_t)(key >> 4) * 1024
                           + f * 512 + q8 * 128 + (key & 15) * 8 + i8;
                kfm_out[off] = f2bf(accs[nt][r] + bs);
            }
        } else if (z == vz) {
            int hh = col >> 6, dim = col & 63;
            int ntg = dim >> 4, l16v = dim & 15;
            int row = row0 + quad * 4;
            int bb = row / Skv; int key = row - bb * Skv;
            size_t off = (size_t)(bb * 4 + hh) * Skv * 64 + (size_t)(key >> 4) * 1024
                       + ntg * 256 + ((key & 15) >> 2) * 64 + l16v * 4;
            ushort4 pk;
            pk.x = f2bf(accs[nt][0] + bs);
            pk.y = f2bf(accs[nt][1] + bs);
            pk.z = f2bf(accs[nt][2] + bs);
            pk.w = f2bf(accs[nt][3] + bs);
            *(ushort4*)(vfm_out + off) = pk;
        } else {
            size_t base = ((size_t)(row0 >> 4) * 8 + blockIdx.y) * 512;
            int g3 = (nt * 2 + (l16 >> 3)) & 3;
            int i = l16 & 7;
            #pragma unroll
            for (int r = 0; r < 4; r++)
                qout[base + (((quad * 4 + r) + 16 * g3) << 3) + i] =
                    f2bf((accs[nt][r] + bs) * scale0);
        }
    }
}

// ---------------- GEMM + bias + residual + LayerNorm (8 waves) ----------------
__global__ __launch_bounds__(512) void k_gemm_ln(const u16* A, const u16* Wfm, const float* bias,
                                                 const float* res, const float* g, const float* beta,
                                                 float* outf, u16* outb, int K) {
    int t = threadIdx.x;
    int w = t >> 6, lane = t & 63;
    int l16 = lane & 15, quad = lane >> 4;
    int row0 = blockIdx.x * 16;
    int Kc = K >> 5;

    f32x4 acc[2];
    acc[0] = (f32x4){0.f, 0.f, 0.f, 0.f};
    acc[1] = (f32x4){0.f, 0.f, 0.f, 0.f};

    const u16* ab = A + (size_t)blockIdx.x * Kc * 512 + lane * 8;
    const u16* wb = Wfm + (size_t)(w * 2) * Kc * 512 + lane * 8;
    #pragma unroll 4
    for (int kc = 0; kc < Kc; kc++) {
        bhalf8 a = *(const bhalf8*)(ab + kc * 512);
        acc[0] = mfma_bf16(a, *(const bhalf8*)(wb + kc * 512), acc[0]);
        acc[1] = mfma_bf16(a, *(const bhalf8*)(wb + (size_t)(Kc + kc) * 512), acc[1]);
    }

    float sr[4] = {0.f, 0.f, 0.f, 0.f}, s2r[4] = {0.f, 0.f, 0.f, 0.f};
    #pragma unroll
    for (int nt = 0; nt < 2; nt++) {
        int col = w * 32 + nt * 16 + l16;
        float bs = bias[col];
        #pragma unroll
        for (int r = 0; r < 4; r++) {
            int row = row0 + quad * 4 + r;
            float v = acc[nt][r] + bs + res[(size_t)row * 256 + col];
            acc[nt][r] = v;
            sr[r] += v; s2r[r] += v * v;
        }
    }
    #pragma unroll
    for (int r = 0; r < 4; r++) {
        #pragma unroll
        for (int off = 8; off >= 1; off >>= 1) {
            sr[r]  += __shfl_xor(sr[r], off, 16);
            s2r[r] += __shfl_xor(s2r[r], off, 16);
        }
    }
    __shared__ float lsm[8][16], lsq[8][16];
    if (l16 == 0) {
        #pragma unroll
        for (int r = 0; r < 4; r++) { lsm[w][quad * 4 + r] = sr[r]; lsq[w][quad * 4 + r] = s2r[r]; }
    }
    __syncthreads();
    float mu[4], rs[4];
    #pragma unroll
    for (int r = 0; r < 4; r++) {
        int ri = quad * 4 + r;
        float ts = 0.f, tq = 0.f;
        #pragma unroll
        for (int ww = 0; ww < 8; ww++) { ts += lsm[ww][ri]; tq += lsq[ww][ri]; }
        mu[r] = ts * (1.f / 256.f);
        float var = tq * (1.f / 256.f) - mu[r] * mu[r];
        rs[r] = rsqrtf(var + 1e-12f);
    }
    size_t base = ((size_t)blockIdx.x * 8 + w) * 512;
    #pragma unroll
    for (int nt = 0; nt < 2; nt++) {
        int col = w * 32 + nt * 16 + l16;
        float gc = g[col], bc = beta[col];
        int g3 = (nt * 2 + (l16 >> 3)) & 3;
        int i = l16 & 7;
        #pragma unroll
        for (int r = 0; r < 4; r++) {
            int row = row0 + quad * 4 + r;
            float yv = (acc[nt][r] - mu[r]) * rs[r] * gc + bc;
            outf[(size_t)row * 256 + col] = yv;
            outb[base + (((quad * 4 + r) + 16 * g3) << 3) + i] = f2bf(yv);
        }
    }
}

// ---------------- fused FFN: GEMM1+GELU -> LDS -> GEMM2 + res + LN -----------
// Round-8 proven version (16 rows/block, 256 blocks = 1/CU). Round-11's
// 32-row variant reverted: 128 blocks left half the CUs idle (+7µs/launch).
__global__ __launch_bounds__(512) void k_ffn(const u16* A, const u16* W1, const float* b1,
                                             const u16* W2, const float* b2,
                                             const float* res, const float* g, const float* beta,
                                             float* outf, u16* outb) {
    int t = threadIdx.x;
    int w = t >> 6, lane = t & 63;
    int l16 = lane & 15, quad = lane >> 4;
    int row0 = blockIdx.x * 16;

    __shared__ u16 f1lds[32 * 512];    // 32 chunks x 512 u16 = 32 KB (afm, K=1024)
    __shared__ float lsm[8][16], lsq[8][16];

    // ---- stage 1: f1 = A @ W1 (K=256, Kc=8), wave w -> 8 n-tiles ----
    f32x4 acc[8];
    #pragma unroll
    for (int nt = 0; nt < 8; nt++) acc[nt] = (f32x4){0.f, 0.f, 0.f, 0.f};
    const u16* ab = A + (size_t)blockIdx.x * 8 * 512 + lane * 8;
    const u16* w1b = W1 + (size_t)(w * 8) * 8 * 512 + lane * 8;
    #pragma unroll
    for (int kc = 0; kc < 8; kc++) {
        bhalf8 a = *(const bhalf8*)(ab + kc * 512);
        #pragma unroll
        for (int nt = 0; nt < 8; nt++)
            acc[nt] = mfma_bf16(a, *(const bhalf8*)(w1b + ((size_t)nt * 8 + kc) * 512), acc[nt]);
    }
    // GELU + pack to LDS afm
    #pragma unroll
    for (int nt = 0; nt < 8; nt++) {
        int col = w * 128 + nt * 16 + l16;
        float bs = b1[col];
        int chunk = w * 4 + (nt >> 1);
        int g3 = (nt * 2 + (l16 >> 3)) & 3;
        int i = l16 & 7;
        #pragma unroll
        for (int r = 0; r < 4; r++) {
            float v = acc[nt][r] + bs;
            float ge = 0.5f * v * (1.f + tanhf(0.7978845608028654f * (v + 0.044715f * v * v * v)));
            f1lds[chunk * 512 + (((quad * 4 + r) + 16 * g3) << 3) + i] = f2bf(ge);
        }
    }
    __syncthreads();

    // ---- stage 2: out = f1 @ W2 (K=1024, Kc=32), wave w -> 2 n-tiles ----
    f32x4 acc2[2];
    acc2[0] = (f32x4){0.f, 0.f, 0.f, 0.f};
    acc2[1] = (f32x4){0.f, 0.f, 0.f, 0.f};
    const u16* w2b = W2 + (size_t)(w * 2) * 32 * 512 + lane * 8;
    #pragma unroll 4
    for (int kc = 0; kc < 32; kc++) {
        bhalf8 a = *(const bhalf8*)&f1lds[kc * 512 + lane * 8];
        acc2[0] = mfma_bf16(a, *(const bhalf8*)(w2b + (size_t)kc * 512), acc2[0]);
        acc2[1] = mfma_bf16(a, *(const bhalf8*)(w2b + (size_t)(32 + kc) * 512), acc2[1]);
    }

    // ---- stage 3: bias + residual + LN ----
    float sr[4] = {0.f, 0.f, 0.f, 0.f}, s2r[4] = {0.f, 0.f, 0.f, 0.f};
    #pragma unroll
    for (int nt = 0; nt < 2; nt++) {
        int col = w * 32 + nt * 16 + l16;
        float bs = b2[col];
        #pragma unroll
        for (int r = 0; r < 4; r++) {
            int row = row0 + quad * 4 + r;
            float v = acc2[nt][r] + bs + res[(size_t)row * 256 + col];
            acc2[nt][r] = v;
            sr[r] += v; s2r[r] += v * v;
        }
    }
    #pragma unroll
    for (int r = 0; r < 4; r++) {
        #pragma unroll
        for (int off = 8; off >= 1; off >>= 1) {
            sr[r]  += __shfl_xor(sr[r], off, 16);
            s2r[r] += __shfl_xor(s2r[r], off, 16);
        }
    }
    if (l16 == 0) {
        #pragma unroll
        for (int r = 0; r < 4; r++) { lsm[w][quad * 4 + r] = sr[r]; lsq[w][quad * 4 + r] = s2r[r]; }
    }
    __syncthreads();
    float mu[4], rs[4];
    #pragma unroll
    for (int r = 0; r < 4; r++) {
        int ri = quad * 4 + r;
        float ts = 0.f, tq = 0.f;
        #pragma unroll
        for (int ww = 0; ww < 8; ww++) { ts += lsm[ww][ri]; tq += lsq[ww][ri]; }
        mu[r] = ts * (1.f / 256.f);
        float var = tq * (1.f / 256.f) - mu[r] * mu[r];
        rs[r] = rsqrtf(var + 1e-12f);
    }
    size_t base = ((size_t)blockIdx.x * 8 + w) * 512;
    #pragma unroll
    for (int nt = 0; nt < 2; nt++) {
        int col = w * 32 + nt * 16 + l16;
        float gc = g[col], bc = beta[col];
        int g3 = (nt * 2 + (l16 >> 3)) & 3;
        int i = l16 & 7;
        #pragma unroll
        for (int r = 0; r < 4; r++) {
            int row = row0 + quad * 4 + r;
            float yv = (acc2[nt][r] - mu[r]) * rs[r] * gc + bc;
            outf[(size_t)row * 256 + col] = yv;
            outb[base + (((quad * 4 + r) + 16 * g3) << 3) + i] = f2bf(yv);
        }
    }
}

// ---------------- flash attention (fragment-major Q/K/V, afm ctx out) ----------
// Verified round-8 structure: 512 thr = 8 waves, TWO 16-row q-tiles, 8-way key
// split, pk2bf inner loop, unroll 2, wave0-serial combine. SETTLED.
__global__ __launch_bounds__(512, 4) void k_attn(const u16* q, const u16* kfm, const u16* vfm,
                                                 u16* ctx, int Sq, int Sk) {
    int bh = blockIdx.x & 7;
    int b = bh >> 2, h = bh & 3;
    int qp = blockIdx.x >> 3;
    int t = threadIdx.x;
    int kw = t >> 6, lane = t & 63;     // kw in [0,8)
    int l16 = lane & 15, quad = lane >> 4;
    int q0 = qp * 32;                   // rows q0 .. q0+31 (two 16-row tiles)

    // stride 20 floats: bank = quad*16 + l16 (mod 32) -> 2-way (free)
    __shared__ float opart[2][7][64][20];
    __shared__ float lsum[2][7][16];

    size_t rt0 = (size_t)((b * Sq + q0) >> 4);
    const u16* qb = q + (rt0 * 8 + h * 2) * 512 + lane * 8;
    bhalf8 bq00 = *(const bhalf8*)(qb);
    bhalf8 bq01 = *(const bhalf8*)(qb + 512);
    bhalf8 bq10 = *(const bhalf8*)(qb + 8 * 512);   // next q-tile: +8 chunks
    bhalf8 bq11 = *(const bhalf8*)(qb + 9 * 512);

    const u16* kwb = kfm + (size_t)(b * 4 + h) * Sk * 64;
    const u16* vwb = vfm + (size_t)(b * 4 + h) * Sk * 64;

    int nT = Sk >> 7;          // 16-key tiles per wave (8-way split)
    int T0 = kw * nT;

    float l0 = 0.f, l1 = 0.f;
    f32x4 o0[4], o1[4];
    #pragma unroll
    for (int nt = 0; nt < 4; nt++) {
        o0[nt] = (f32x4){0.f, 0.f, 0.f, 0.f};
        o1[nt] = (f32x4){0.f, 0.f, 0.f, 0.f};
    }

    #pragma unroll 2
    for (int T = T0; T < T0 + nT; T++) {
        const u16* kt = kwb + (size_t)T * 1024;
        bhalf8 a0 = *(const bhalf8*)(kt + lane * 8);
        bhalf8 a1 = *(const bhalf8*)(kt + 512 + lane * 8);
        f32x4 s0 = (f32x4){0.f, 0.f, 0.f, 0.f};
        f32x4 s1 = (f32x4){0.f, 0.f, 0.f, 0.f};
        s0 = mfma_bf16(a0, bq00, s0);
        s0 = mfma_bf16(a1, bq01, s0);
        s1 = mfma_bf16(a0, bq10, s1);
        s1 = mfma_bf16(a1, bq11, s1);

        float p0[4], p1[4], ps0 = 0.f, ps1 = 0.f;
        #pragma unroll
        for (int r = 0; r < 4; r++) {
            p0[r] = exp2f(s0[r] - 11.5415603f);
            ps0 += p0[r];
            p1[r] = exp2f(s1[r] - 11.5415603f);
            ps1 += p1[r];
        }
        l0 += ps0; l1 += ps1;

        union { bhalf4 v; unsigned u[2]; } bp0, bp1;
        bp0.u[0] = pk2bf(p0[0], p0[1]);
        bp0.u[1] = pk2bf(p0[2], p0[3]);
        bp1.u[0] = pk2bf(p1[0], p1[1]);
        bp1.u[1] = pk2bf(p1[2], p1[3]);

        const u16* vts = vwb + (size_t)T * 1024 + quad * 64 + l16 * 4;
        #pragma unroll
        for (int nt = 0; nt < 4; nt++) {
            bhalf4 va = *(const bhalf4*)(vts + nt * 256);
            o0[nt] = mfma16_bf16(va, bp0.v, o0[nt]);
            o1[nt] = mfma16_bf16(va, bp1.v, o1[nt]);
        }
    }

    float lc0 = l0, lc1 = l1;
    lc0 += __shfl_xor(lc0, 16, 64);
    lc0 += __shfl_xor(lc0, 32, 64);
    lc1 += __shfl_xor(lc1, 16, 64);
    lc1 += __shfl_xor(lc1, 32, 64);

    if (kw > 0) {
        #pragma unroll
        for (int nt = 0; nt < 4; nt++)
            #pragma unroll
            for (int r = 0; r < 4; r++) {
                opart[0][kw - 1][nt * 16 + quad * 4 + r][l16] = o0[nt][r];
                opart[1][kw - 1][nt * 16 + quad * 4 + r][l16] = o1[nt][r];
            }
        if (quad == 0) {
            lsum[0][kw - 1][l16] = lc0;
            lsum[1][kw - 1][l16] = lc1;
        }
    }
    __syncthreads();
    if (kw == 0) {
        float L0 = lc0, L1 = lc1;
        #pragma unroll
        for (int ww = 0; ww < 7; ww++) {
            L0 += lsum[0][ww][l16];
            L1 += lsum[1][ww][l16];
        }
        float invL0 = 1.f / L0;
        float invL1 = 1.f / L1;
        #pragma unroll
        for (int nt = 0; nt < 4; nt++) {
            ushort4 pkv0, pkv1;
            #pragma unroll
            for (int r = 0; r < 4; r++) {
                float v0 = o0[nt][r];
                float v1 = o1[nt][r];
                #pragma unroll
                for (int ww = 0; ww < 7; ww++) {
                    v0 += opart[0][ww][nt * 16 + quad * 4 + r][l16];
                    v1 += opart[1][ww][nt * 16 + quad * 4 + r][l16];
                }
                ((u16*)&pkv0)[r] = f2bf(v0 * invL0);
                ((u16*)&pkv1)[r] = f2bf(v1 * invL1);
            }
            size_t ce = ((l16 + 16 * ((nt * 2 + (quad >> 1)) & 3)) << 3) + (quad & 1) * 4;
            size_t off0 = (rt0 * 8 + (h * 2 + (nt >> 1))) * 512 + ce;
            size_t off1 = ((rt0 + 1) * 8 + (h * 2 + (nt >> 1))) * 512 + ce;
            *(ushort4*)(ctx + off0) = pkv0;
            *(ushort4*)(ctx + off1) = pkv1;
        }
    }
}

// ---------------- host ----------------
extern "C" void kernel_launch(void* const* d_in, const int* in_sizes, int n_in,
                              void* d_out, int out_size, void* d_ws, size_t ws_size,
                              hipStream_t stream) {
    const float* x        = (const float*)d_in[0];
    const float* y        = (const float*)d_in[1];
    const float* pos      = (const float*)d_in[2];
    const float* sqkv_w   = (const float*)d_in[3];
    const float* sqkv_b   = (const float*)d_in[4];
    const float* so_w     = (const float*)d_in[5];
    const float* so_b     = (const float*)d_in[6];
    const float* cqkv_w   = (const float*)d_in[7];
    const float* cqkv_b   = (const float*)d_in[8];
    const float* co_w     = (const float*)d_in[9];
    const float* co_b     = (const float*)d_in[10];
    const float* ffn_w1   = (const float*)d_in[11];
    const float* ffn_b1   = (const float*)d_in[12];
    const float* ffn_w2   = (const float*)d_in[13];
    const float* ffn_b2   = (const float*)d_in[14];
    const float* ln_g     = (const float*)d_in[15];
    const float* ln_b     = (const float*)d_in[16];

    char* w = (char*)d_ws;
    auto alloc = [&](size_t bytes) { char* p = w; w += (bytes + 255) & ~(size_t)255; return p; };

    u16* wt_sqkv = (u16*)alloc(18ull * 65536 * 2);
    u16* wt_so   = (u16*)alloc(6ull  * 65536 * 2);
    u16* wt_cqkv = (u16*)alloc(18ull * 65536 * 2);
    u16* wt_co   = (u16*)alloc(6ull  * 65536 * 2);
    u16* wt_f1   = (u16*)alloc(6ull  * 262144 * 2);
    u16* wt_f2   = (u16*)alloc(6ull  * 262144 * 2);
    u16* xp      = (u16*)alloc(2097152ull * 2);
    float* hf    = (float*)alloc(1048576ull * 4);
    u16* hb      = (u16*)alloc(1048576ull * 2);
    u16* qbuf    = (u16*)alloc(1048576ull * 2);
    u16* kfm     = (u16*)alloc(2097152ull * 2);
    u16* vfm     = (u16*)alloc(2097152ull * 2);
    u16* ctx     = (u16*)alloc(1048576ull * 2);
    u16* kfm_all = (u16*)alloc(6ull * 2097152 * 2);   // per-layer cross K (24 MB)
    u16* vfm_all = (u16*)alloc(6ull * 2097152 * 2);   // per-layer cross V (24 MB)

    k_wtrans_fm<<<dim3(256, 18), 256, 0, stream>>>(sqkv_w, wt_sqkv, 256, 256);
    k_wtrans_fm<<<dim3(256, 6),  256, 0, stream>>>(so_w,   wt_so,   256, 256);
    k_wtrans_fm<<<dim3(256, 18), 256, 0, stream>>>(cqkv_w, wt_cqkv, 256, 256);
    k_wtrans_fm<<<dim3(256, 6),  256, 0, stream>>>(co_w,   wt_co,   256, 256);
    k_wtrans_fm<<<dim3(1024, 6), 256, 0, stream>>>(ffn_w1, wt_f1,   256, 1024);
    k_wtrans_fm<<<dim3(1024, 6), 256, 0, stream>>>(ffn_w2, wt_f2,   1024, 256);
    k_addpos<<<dim3(8192), 256, 0, stream>>>(x, pos, xp);
    k_inith<<<dim3(4096), 256, 0, stream>>>(y, hf, hb);
    // cross K/V for all 6 layers: layer-invariant A=xp, fused K+V, 2 col-pairs
    k_kv_pre<<<dim3(128, 4, 6), 256, 0, stream>>>(xp, wt_cqkv, cqkv_b, kfm_all, vfm_all);

    const float qscale = 0.125f * 1.44269504f;  // 1/sqrt(64) * log2(e)

    for (int i = 0; i < 6; i++) {
        // ---- self attention ----
        k_gemm_qkv<<<dim3(64, 8, 3), 256, 0, stream>>>(hb, hb,
            wt_sqkv + (size_t)i * 3 * 65536, sqkv_b + i * 768,
            qbuf, kfm, vfm, 256, 65536, 256, qscale, 1, 2, 2048, 4096);
        k_attn<<<dim3(512), 512, 0, stream>>>(qbuf, kfm, vfm, ctx, 2048, 2048);
        k_gemm_ln<<<dim3(256), 512, 0, stream>>>(ctx, wt_so + (size_t)i * 65536,
            so_b + i * 256, hf, ln_g + (i * 3 + 0) * 256, ln_b + (i * 3 + 0) * 256,
            hf, hb, 256);

        // ---- cross attention (K/V precomputed; only q GEMM in-loop) ----
        k_gemm_qkv<<<dim3(64, 8, 1), 256, 0, stream>>>(hb, xp,
            wt_cqkv + (size_t)i * 3 * 65536, cqkv_b + i * 768,
            qbuf, kfm, vfm, 256, 65536, 256, qscale, 1, 2, 4096, 4096);
        k_attn<<<dim3(512), 512, 0, stream>>>(qbuf,
            kfm_all + (size_t)i * 2097152, vfm_all + (size_t)i * 2097152, ctx, 2048, 4096);
        k_gemm_ln<<<dim3(256), 512, 0, stream>>>(ctx, wt_co + (size_t)i * 65536,
            co_b + i * 256, hf, ln_g + (i * 3 + 1) * 256, ln_b + (i * 3 + 1) * 256,
            hf, hb, 256);

        // ---- fused FFN (round-8 proven: 16 rows/block, 256 blocks) ----
        float* dst = (i == 5) ? (float*)d_out : hf;
        k_ffn<<<dim3(256), 512, 0, stream>>>(hb, wt_f1 + (size_t)i * 262144,
            ffn_b1 + i * 1024, wt_f2 + (size_t)i * 262144, ffn_b2 + i * 256,
            hf, ln_g + (i * 3 + 2) * 256, ln_b + (i * 3 + 2) * 256, dst, hb);
    }
}

// Round 13
// 857.372 us; speedup vs baseline: 3.3555x; 1.0308x over previous
//
#include <hip/hip_runtime.h>
#include <hip/hip_bf16.h>

typedef unsigned short u16;
typedef __attribute__((ext_vector_type(8))) short bhalf8;
typedef __attribute__((ext_vector_type(4))) short bhalf4;
typedef __attribute__((ext_vector_type(4))) float f32x4;

__device__ inline f32x4 mfma_bf16(bhalf8 a, bhalf8 b, f32x4 c) {
    return __builtin_amdgcn_mfma_f32_16x16x32_bf16(a, b, c, 0, 0, 0);
}
__device__ inline f32x4 mfma16_bf16(bhalf4 a, bhalf4 b, f32x4 c) {
    return __builtin_amdgcn_mfma_f32_16x16x16bf16_1k(a, b, c, 0, 0, 0);
}

__device__ inline u16 f2bf(float f) {
    union { float f; unsigned u; } v; v.f = f;
    unsigned u = v.u;
    return (u16)((u + 0x7fff + ((u >> 16) & 1)) >> 16);
}
// native packed f32x2 -> bf16x2 (RNE; identical rounding to f2bf on finite vals)
__device__ inline unsigned pk2bf(float lo, float hi) {
    union { __hip_bfloat162 h; unsigned u; } v;
    v.h = __float22bfloat162_rn(float2{lo, hi});
    return v.u;
}

// Fragment-major (afm) layout for [M][C] bf16: tile t=row>>4, chunk kc=col>>5,
// lane' = (row&15) + 16*((col>>3)&3), elem i = col&7.
__device__ inline size_t afm_off(int row, int col, int Cc) {
    return ((size_t)((row >> 4) * Cc + (col >> 5))) * 512
         + (((row & 15) + 16 * ((col >> 3) & 3)) << 3) + (col & 7);
}

// ---------------- prologue kernels ----------------

__global__ __launch_bounds__(256) void k_wtrans_fm(const float* in, u16* out, int rows, int cols) {
    int mat = blockIdx.y;
    size_t rc = (size_t)rows * cols;
    size_t idx = (size_t)blockIdx.x * 256 + threadIdx.x;
    if (idx >= rc) return;
    int r = (int)(idx / cols), c = (int)(idx % cols);   // r=k, c=n
    size_t off = ((size_t)((c >> 4) * (rows >> 5) + (r >> 5))) * 512
               + (((c & 15) + 16 * ((r >> 3) & 3)) << 3) + (r & 7);
    out[mat * rc + off] = f2bf(in[mat * rc + idx]);
}

__global__ __launch_bounds__(256) void k_addpos(const float* x, const float* pos, u16* xp) {
    size_t idx = (size_t)blockIdx.x * 256 + threadIdx.x;
    size_t p = idx & ((size_t)4096 * 256 - 1);
    int row = (int)(idx >> 8), col = (int)(idx & 255);
    xp[afm_off(row, col, 8)] = f2bf(x[idx] + pos[p]);
}

__global__ __launch_bounds__(256) void k_inith(const float* y, float* h, u16* hb) {
    size_t idx = (size_t)blockIdx.x * 256 + threadIdx.x;
    float v = y[idx];
    h[idx] = v;
    int row = (int)(idx >> 8), col = (int)(idx & 255);
    hb[afm_off(row, col, 8)] = f2bf(v);
}

// ---------------- precompute cross K/V for ALL layers (layer-invariant A=xp) ----
// Round-8 VERIFIED version (43.8µs): FUSED K+V, grid (128,8,6); each block
// loads its A rows once and applies both W_k and W_v (4 accs, 4 MFMAs/kc).
// SETTLED. (Round-9 LDS-staging: 9% occ. Round-12 2-col-pair: ILP/latency
// collapse, 3.0 TB/s. Small blocks + many of them wins at this L2 wall.)
__global__ __launch_bounds__(256) void k_kv_pre(const u16* A2, const u16* Wall, const float* ball,
                                                u16* kfm_all, u16* vfm_all) {
    const int Skv = 4096;
    int layer = blockIdx.z;
    int wave = threadIdx.x >> 6, lane = threadIdx.x & 63;
    int l16 = lane & 15, quad = lane >> 4;
    int row0 = blockIdx.x * 64 + wave * 16;
    int col0 = blockIdx.y * 32;
    const u16* Wk = Wall + (size_t)layer * 3 * 65536 + 65536;
    const u16* Wv = Wk + 65536;
    const float* bk = ball + layer * 768 + 256;
    const float* bv = bk + 256;
    u16* kout = kfm_all + (size_t)layer * 2097152;
    u16* vout = vfm_all + (size_t)layer * 2097152;
    const int Kc = 8;

    f32x4 acck0 = (f32x4){0.f, 0.f, 0.f, 0.f};
    f32x4 acck1 = (f32x4){0.f, 0.f, 0.f, 0.f};
    f32x4 accv0 = (f32x4){0.f, 0.f, 0.f, 0.f};
    f32x4 accv1 = (f32x4){0.f, 0.f, 0.f, 0.f};
    const u16* ab  = A2 + (size_t)(row0 >> 4) * Kc * 512 + lane * 8;
    const u16* wk0 = Wk + (size_t)(col0 >> 4) * Kc * 512 + lane * 8;
    const u16* wk1 = wk0 + (size_t)Kc * 512;
    const u16* wv0 = Wv + (size_t)(col0 >> 4) * Kc * 512 + lane * 8;
    const u16* wv1 = wv0 + (size_t)Kc * 512;
    #pragma unroll
    for (int kc = 0; kc < Kc; kc++) {
        bhalf8 a = *(const bhalf8*)(ab + kc * 512);
        acck0 = mfma_bf16(a, *(const bhalf8*)(wk0 + kc * 512), acck0);
        acck1 = mfma_bf16(a, *(const bhalf8*)(wk1 + kc * 512), acck1);
        accv0 = mfma_bf16(a, *(const bhalf8*)(wv0 + kc * 512), accv0);
        accv1 = mfma_bf16(a, *(const bhalf8*)(wv1 + kc * 512), accv1);
    }

    // ---- K epilogue (verbatim) ----
    {
        f32x4 accs[2] = {acck0, acck1};
        #pragma unroll
        for (int nt = 0; nt < 2; nt++) {
            int col = col0 + nt * 16 + l16;
            float bs = bk[col];
            int hh = col >> 6, dim = col & 63;
            int f = dim >> 5, q8 = (dim >> 3) & 3, i8 = dim & 7;
            #pragma unroll
            for (int r = 0; r < 4; r++) {
                int row = row0 + quad * 4 + r;
                int bb = row / Skv; int key = row - bb * Skv;
                size_t off = (size_t)(bb * 4 + hh) * Skv * 64 + (size_t)(key >> 4) * 1024
                           + f * 512 + q8 * 128 + (key & 15) * 8 + i8;
                kout[off] = f2bf(accs[nt][r] + bs);
            }
        }
    }
    // ---- V epilogue (verbatim) ----
    {
        f32x4 accs[2] = {accv0, accv1};
        #pragma unroll
        for (int nt = 0; nt < 2; nt++) {
            int col = col0 + nt * 16 + l16;
            float bs = bv[col];
            int hh = col >> 6, dim = col & 63;
            int ntg = dim >> 4, l16v = dim & 15;
            int row = row0 + quad * 4;
            int bb = row / Skv; int key = row - bb * Skv;
            size_t off = (size_t)(bb * 4 + hh) * Skv * 64 + (size_t)(key >> 4) * 1024
                       + ntg * 256 + ((key & 15) >> 2) * 64 + l16v * 4;
            ushort4 pk;
            pk.x = f2bf(accs[nt][0] + bs);
            pk.y = f2bf(accs[nt][1] + bs);
            pk.z = f2bf(accs[nt][2] + bs);
            pk.w = f2bf(accs[nt][3] + bs);
            *(ushort4*)(vout + off) = pk;
        }
    }
}

// ---------------- QKV GEMM (all operands fragment-major) ----------------
__global__ __launch_bounds__(256) void k_gemm_qkv(const u16* A0, const u16* A2,
                                                  const u16* Wfm0, const float* bias0,
                                                  u16* qout, u16* kfm_out, u16* vfm_out,
                                                  int K, long wz, long bz, float scale0,
                                                  int kz, int vz, int Skv, int M0) {
    int z = blockIdx.z;
    int wave = threadIdx.x >> 6, lane = threadIdx.x & 63;
    int l16 = lane & 15, quad = lane >> 4;
    int row0 = blockIdx.x * 64 + wave * 16;
    int col0 = blockIdx.y * 32;
    const u16* A;
    if (z == 0) { if (row0 >= M0) return; A = A0; } else { A = A2; }
    const u16* Wfm = Wfm0 + (size_t)z * wz;
    const float* bias = bias0 + (size_t)z * bz;
    int Kc = K >> 5;

    f32x4 acc0 = (f32x4){0.f, 0.f, 0.f, 0.f};
    f32x4 acc1 = (f32x4){0.f, 0.f, 0.f, 0.f};
    const u16* ab = A + (size_t)(row0 >> 4) * Kc * 512 + lane * 8;
    const u16* wb0 = Wfm + (size_t)(col0 >> 4) * Kc * 512 + lane * 8;
    const u16* wb1 = wb0 + (size_t)Kc * 512;
    #pragma unroll 4
    for (int kc = 0; kc < Kc; kc++) {
        bhalf8 a = *(const bhalf8*)(ab + kc * 512);
        acc0 = mfma_bf16(a, *(const bhalf8*)(wb0 + kc * 512), acc0);
        acc1 = mfma_bf16(a, *(const bhalf8*)(wb1 + kc * 512), acc1);
    }

    f32x4 accs[2] = {acc0, acc1};
    #pragma unroll
    for (int nt = 0; nt < 2; nt++) {
        int col = col0 + nt * 16 + l16;
        float bs = bias[col];
        if (z == kz) {
            int hh = col >> 6, dim = col & 63;
            int f = dim >> 5, q8 = (dim >> 3) & 3, i8 = dim & 7;
            #pragma unroll
            for (int r = 0; r < 4; r++) {
                int row = row0 + quad * 4 + r;
                int bb = row / Skv; int key = row - bb * Skv;
                size_t off = (size_t)(bb * 4 + hh) * Skv * 64 + (size_t)(key >> 4) * 1024
                           + f * 512 + q8 * 128 + (key & 15) * 8 + i8;
                kfm_out[off] = f2bf(accs[nt][r] + bs);
            }
        } else if (z == vz) {
            int hh = col >> 6, dim = col & 63;
            int ntg = dim >> 4, l16v = dim & 15;
            int row = row0 + quad * 4;
            int bb = row / Skv; int key = row - bb * Skv;
            size_t off = (size_t)(bb * 4 + hh) * Skv * 64 + (size_t)(key >> 4) * 1024
                       + ntg * 256 + ((key & 15) >> 2) * 64 + l16v * 4;
            ushort4 pk;
            pk.x = f2bf(accs[nt][0] + bs);
            pk.y = f2bf(accs[nt][1] + bs);
            pk.z = f2bf(accs[nt][2] + bs);
            pk.w = f2bf(accs[nt][3] + bs);
            *(ushort4*)(vfm_out + off) = pk;
        } else {
            size_t base = ((size_t)(row0 >> 4) * 8 + blockIdx.y) * 512;
            int g3 = (nt * 2 + (l16 >> 3)) & 3;
            int i = l16 & 7;
            #pragma unroll
            for (int r = 0; r < 4; r++)
                qout[base + (((quad * 4 + r) + 16 * g3) << 3) + i] =
                    f2bf((accs[nt][r] + bs) * scale0);
        }
    }
}

// ---------------- GEMM + bias + residual + LayerNorm (8 waves) ----------------
__global__ __launch_bounds__(512) void k_gemm_ln(const u16* A, const u16* Wfm, const float* bias,
                                                 const float* res, const float* g, const float* beta,
                                                 float* outf, u16* outb, int K) {
    int t = threadIdx.x;
    int w = t >> 6, lane = t & 63;
    int l16 = lane & 15, quad = lane >> 4;
    int row0 = blockIdx.x * 16;
    int Kc = K >> 5;

    f32x4 acc[2];
    acc[0] = (f32x4){0.f, 0.f, 0.f, 0.f};
    acc[1] = (f32x4){0.f, 0.f, 0.f, 0.f};

    const u16* ab = A + (size_t)blockIdx.x * Kc * 512 + lane * 8;
    const u16* wb = Wfm + (size_t)(w * 2) * Kc * 512 + lane * 8;
    #pragma unroll 4
    for (int kc = 0; kc < Kc; kc++) {
        bhalf8 a = *(const bhalf8*)(ab + kc * 512);
        acc[0] = mfma_bf16(a, *(const bhalf8*)(wb + kc * 512), acc[0]);
        acc[1] = mfma_bf16(a, *(const bhalf8*)(wb + (size_t)(Kc + kc) * 512), acc[1]);
    }

    float sr[4] = {0.f, 0.f, 0.f, 0.f}, s2r[4] = {0.f, 0.f, 0.f, 0.f};
    #pragma unroll
    for (int nt = 0; nt < 2; nt++) {
        int col = w * 32 + nt * 16 + l16;
        float bs = bias[col];
        #pragma unroll
        for (int r = 0; r < 4; r++) {
            int row = row0 + quad * 4 + r;
            float v = acc[nt][r] + bs + res[(size_t)row * 256 + col];
            acc[nt][r] = v;
            sr[r] += v; s2r[r] += v * v;
        }
    }
    #pragma unroll
    for (int r = 0; r < 4; r++) {
        #pragma unroll
        for (int off = 8; off >= 1; off >>= 1) {
            sr[r]  += __shfl_xor(sr[r], off, 16);
            s2r[r] += __shfl_xor(s2r[r], off, 16);
        }
    }
    __shared__ float lsm[8][16], lsq[8][16];
    if (l16 == 0) {
        #pragma unroll
        for (int r = 0; r < 4; r++) { lsm[w][quad * 4 + r] = sr[r]; lsq[w][quad * 4 + r] = s2r[r]; }
    }
    __syncthreads();
    float mu[4], rs[4];
    #pragma unroll
    for (int r = 0; r < 4; r++) {
        int ri = quad * 4 + r;
        float ts = 0.f, tq = 0.f;
        #pragma unroll
        for (int ww = 0; ww < 8; ww++) { ts += lsm[ww][ri]; tq += lsq[ww][ri]; }
        mu[r] = ts * (1.f / 256.f);
        float var = tq * (1.f / 256.f) - mu[r] * mu[r];
        rs[r] = rsqrtf(var + 1e-12f);
    }
    size_t base = ((size_t)blockIdx.x * 8 + w) * 512;
    #pragma unroll
    for (int nt = 0; nt < 2; nt++) {
        int col = w * 32 + nt * 16 + l16;
        float gc = g[col], bc = beta[col];
        int g3 = (nt * 2 + (l16 >> 3)) & 3;
        int i = l16 & 7;
        #pragma unroll
        for (int r = 0; r < 4; r++) {
            int row = row0 + quad * 4 + r;
            float yv = (acc[nt][r] - mu[r]) * rs[r] * gc + bc;
            outf[(size_t)row * 256 + col] = yv;
            outb[base + (((quad * 4 + r) + 16 * g3) << 3) + i] = f2bf(yv);
        }
    }
}

// ---------------- fused FFN: GEMM1+GELU -> LDS -> GEMM2 + res + LN -----------
// Round-8 proven version (16 rows/block, 256 blocks = 1/CU). SETTLED.
__global__ __launch_bounds__(512) void k_ffn(const u16* A, const u16* W1, const float* b1,
                                             const u16* W2, const float* b2,
                                             const float* res, const float* g, const float* beta,
                                             float* outf, u16* outb) {
    int t = threadIdx.x;
    int w = t >> 6, lane = t & 63;
    int l16 = lane & 15, quad = lane >> 4;
    int row0 = blockIdx.x * 16;

    __shared__ u16 f1lds[32 * 512];    // 32 chunks x 512 u16 = 32 KB (afm, K=1024)
    __shared__ float lsm[8][16], lsq[8][16];

    // ---- stage 1: f1 = A @ W1 (K=256, Kc=8), wave w -> 8 n-tiles ----
    f32x4 acc[8];
    #pragma unroll
    for (int nt = 0; nt < 8; nt++) acc[nt] = (f32x4){0.f, 0.f, 0.f, 0.f};
    const u16* ab = A + (size_t)blockIdx.x * 8 * 512 + lane * 8;
    const u16* w1b = W1 + (size_t)(w * 8) * 8 * 512 + lane * 8;
    #pragma unroll
    for (int kc = 0; kc < 8; kc++) {
        bhalf8 a = *(const bhalf8*)(ab + kc * 512);
        #pragma unroll
        for (int nt = 0; nt < 8; nt++)
            acc[nt] = mfma_bf16(a, *(const bhalf8*)(w1b + ((size_t)nt * 8 + kc) * 512), acc[nt]);
    }
    // GELU + pack to LDS afm
    #pragma unroll
    for (int nt = 0; nt < 8; nt++) {
        int col = w * 128 + nt * 16 + l16;
        float bs = b1[col];
        int chunk = w * 4 + (nt >> 1);
        int g3 = (nt * 2 + (l16 >> 3)) & 3;
        int i = l16 & 7;
        #pragma unroll
        for (int r = 0; r < 4; r++) {
            float v = acc[nt][r] + bs;
            float ge = 0.5f * v * (1.f + tanhf(0.7978845608028654f * (v + 0.044715f * v * v * v)));
            f1lds[chunk * 512 + (((quad * 4 + r) + 16 * g3) << 3) + i] = f2bf(ge);
        }
    }
    __syncthreads();

    // ---- stage 2: out = f1 @ W2 (K=1024, Kc=32), wave w -> 2 n-tiles ----
    f32x4 acc2[2];
    acc2[0] = (f32x4){0.f, 0.f, 0.f, 0.f};
    acc2[1] = (f32x4){0.f, 0.f, 0.f, 0.f};
    const u16* w2b = W2 + (size_t)(w * 2) * 32 * 512 + lane * 8;
    #pragma unroll 4
    for (int kc = 0; kc < 32; kc++) {
        bhalf8 a = *(const bhalf8*)&f1lds[kc * 512 + lane * 8];
        acc2[0] = mfma_bf16(a, *(const bhalf8*)(w2b + (size_t)kc * 512), acc2[0]);
        acc2[1] = mfma_bf16(a, *(const bhalf8*)(w2b + (size_t)(32 + kc) * 512), acc2[1]);
    }

    // ---- stage 3: bias + residual + LN ----
    float sr[4] = {0.f, 0.f, 0.f, 0.f}, s2r[4] = {0.f, 0.f, 0.f, 0.f};
    #pragma unroll
    for (int nt = 0; nt < 2; nt++) {
        int col = w * 32 + nt * 16 + l16;
        float bs = b2[col];
        #pragma unroll
        for (int r = 0; r < 4; r++) {
            int row = row0 + quad * 4 + r;
            float v = acc2[nt][r] + bs + res[(size_t)row * 256 + col];
            acc2[nt][r] = v;
            sr[r] += v; s2r[r] += v * v;
        }
    }
    #pragma unroll
    for (int r = 0; r < 4; r++) {
        #pragma unroll
        for (int off = 8; off >= 1; off >>= 1) {
            sr[r]  += __shfl_xor(sr[r], off, 16);
            s2r[r] += __shfl_xor(s2r[r], off, 16);
        }
    }
    if (l16 == 0) {
        #pragma unroll
        for (int r = 0; r < 4; r++) { lsm[w][quad * 4 + r] = sr[r]; lsq[w][quad * 4 + r] = s2r[r]; }
    }
    __syncthreads();
    float mu[4], rs[4];
    #pragma unroll
    for (int r = 0; r < 4; r++) {
        int ri = quad * 4 + r;
        float ts = 0.f, tq = 0.f;
        #pragma unroll
        for (int ww = 0; ww < 8; ww++) { ts += lsm[ww][ri]; tq += lsq[ww][ri]; }
        mu[r] = ts * (1.f / 256.f);
        float var = tq * (1.f / 256.f) - mu[r] * mu[r];
        rs[r] = rsqrtf(var + 1e-12f);
    }
    size_t base = ((size_t)blockIdx.x * 8 + w) * 512;
    #pragma unroll
    for (int nt = 0; nt < 2; nt++) {
        int col = w * 32 + nt * 16 + l16;
        float gc = g[col], bc = beta[col];
        int g3 = (nt * 2 + (l16 >> 3)) & 3;
        int i = l16 & 7;
        #pragma unroll
        for (int r = 0; r < 4; r++) {
            int row = row0 + quad * 4 + r;
            float yv = (acc2[nt][r] - mu[r]) * rs[r] * gc + bc;
            outf[(size_t)row * 256 + col] = yv;
            outb[base + (((quad * 4 + r) + 16 * g3) << 3) + i] = f2bf(yv);
        }
    }
}

// ---------------- flash attention (fragment-major Q/K/V, afm ctx out) ----------
// Verified round-8 structure: 512 thr = 8 waves, TWO 16-row q-tiles, 8-way key
// split, pk2bf inner loop, unroll 2, wave0-serial combine. SETTLED.
__global__ __launch_bounds__(512, 4) void k_attn(const u16* q, const u16* kfm, const u16* vfm,
                                                 u16* ctx, int Sq, int Sk) {
    int bh = blockIdx.x & 7;
    int b = bh >> 2, h = bh & 3;
    int qp = blockIdx.x >> 3;
    int t = threadIdx.x;
    int kw = t >> 6, lane = t & 63;     // kw in [0,8)
    int l16 = lane & 15, quad = lane >> 4;
    int q0 = qp * 32;                   // rows q0 .. q0+31 (two 16-row tiles)

    // stride 20 floats: bank = quad*16 + l16 (mod 32) -> 2-way (free)
    __shared__ float opart[2][7][64][20];
    __shared__ float lsum[2][7][16];

    size_t rt0 = (size_t)((b * Sq + q0) >> 4);
    const u16* qb = q + (rt0 * 8 + h * 2) * 512 + lane * 8;
    bhalf8 bq00 = *(const bhalf8*)(qb);
    bhalf8 bq01 = *(const bhalf8*)(qb + 512);
    bhalf8 bq10 = *(const bhalf8*)(qb + 8 * 512);   // next q-tile: +8 chunks
    bhalf8 bq11 = *(const bhalf8*)(qb + 9 * 512);

    const u16* kwb = kfm + (size_t)(b * 4 + h) * Sk * 64;
    const u16* vwb = vfm + (size_t)(b * 4 + h) * Sk * 64;

    int nT = Sk >> 7;          // 16-key tiles per wave (8-way split)
    int T0 = kw * nT;

    float l0 = 0.f, l1 = 0.f;
    f32x4 o0[4], o1[4];
    #pragma unroll
    for (int nt = 0; nt < 4; nt++) {
        o0[nt] = (f32x4){0.f, 0.f, 0.f, 0.f};
        o1[nt] = (f32x4){0.f, 0.f, 0.f, 0.f};
    }

    #pragma unroll 2
    for (int T = T0; T < T0 + nT; T++) {
        const u16* kt = kwb + (size_t)T * 1024;
        bhalf8 a0 = *(const bhalf8*)(kt + lane * 8);
        bhalf8 a1 = *(const bhalf8*)(kt + 512 + lane * 8);
        f32x4 s0 = (f32x4){0.f, 0.f, 0.f, 0.f};
        f32x4 s1 = (f32x4){0.f, 0.f, 0.f, 0.f};
        s0 = mfma_bf16(a0, bq00, s0);
        s0 = mfma_bf16(a1, bq01, s0);
        s1 = mfma_bf16(a0, bq10, s1);
        s1 = mfma_bf16(a1, bq11, s1);

        float p0[4], p1[4], ps0 = 0.f, ps1 = 0.f;
        #pragma unroll
        for (int r = 0; r < 4; r++) {
            p0[r] = exp2f(s0[r] - 11.5415603f);
            ps0 += p0[r];
            p1[r] = exp2f(s1[r] - 11.5415603f);
            ps1 += p1[r];
        }
        l0 += ps0; l1 += ps1;

        union { bhalf4 v; unsigned u[2]; } bp0, bp1;
        bp0.u[0] = pk2bf(p0[0], p0[1]);
        bp0.u[1] = pk2bf(p0[2], p0[3]);
        bp1.u[0] = pk2bf(p1[0], p1[1]);
        bp1.u[1] = pk2bf(p1[2], p1[3]);

        const u16* vts = vwb + (size_t)T * 1024 + quad * 64 + l16 * 4;
        #pragma unroll
        for (int nt = 0; nt < 4; nt++) {
            bhalf4 va = *(const bhalf4*)(vts + nt * 256);
            o0[nt] = mfma16_bf16(va, bp0.v, o0[nt]);
            o1[nt] = mfma16_bf16(va, bp1.v, o1[nt]);
        }
    }

    float lc0 = l0, lc1 = l1;
    lc0 += __shfl_xor(lc0, 16, 64);
    lc0 += __shfl_xor(lc0, 32, 64);
    lc1 += __shfl_xor(lc1, 16, 64);
    lc1 += __shfl_xor(lc1, 32, 64);

    if (kw > 0) {
        #pragma unroll
        for (int nt = 0; nt < 4; nt++)
            #pragma unroll
            for (int r = 0; r < 4; r++) {
                opart[0][kw - 1][nt * 16 + quad * 4 + r][l16] = o0[nt][r];
                opart[1][kw - 1][nt * 16 + quad * 4 + r][l16] = o1[nt][r];
            }
        if (quad == 0) {
            lsum[0][kw - 1][l16] = lc0;
            lsum[1][kw - 1][l16] = lc1;
        }
    }
    __syncthreads();
    if (kw == 0) {
        float L0 = lc0, L1 = lc1;
        #pragma unroll
        for (int ww = 0; ww < 7; ww++) {
            L0 += lsum[0][ww][l16];
            L1 += lsum[1][ww][l16];
        }
        float invL0 = 1.f / L0;
        float invL1 = 1.f / L1;
        #pragma unroll
        for (int nt = 0; nt < 4; nt++) {
            ushort4 pkv0, pkv1;
            #pragma unroll
            for (int r = 0; r < 4; r++) {
                float v0 = o0[nt][r];
                float v1 = o1[nt][r];
                #pragma unroll
                for (int ww = 0; ww < 7; ww++) {
                    v0 += opart[0][ww][nt * 16 + quad * 4 + r][l16];
                    v1 += opart[1][ww][nt * 16 + quad * 4 + r][l16];
                }
                ((u16*)&pkv0)[r] = f2bf(v0 * invL0);
                ((u16*)&pkv1)[r] = f2bf(v1 * invL1);
            }
            size_t ce = ((l16 + 16 * ((nt * 2 + (quad >> 1)) & 3)) << 3) + (quad & 1) * 4;
            size_t off0 = (rt0 * 8 + (h * 2 + (nt >> 1))) * 512 + ce;
            size_t off1 = ((rt0 + 1) * 8 + (h * 2 + (nt >> 1))) * 512 + ce;
            *(ushort4*)(ctx + off0) = pkv0;
            *(ushort4*)(ctx + off1) = pkv1;
        }
    }
}

// ---------------- host ----------------
extern "C" void kernel_launch(void* const* d_in, const int* in_sizes, int n_in,
                              void* d_out, int out_size, void* d_ws, size_t ws_size,
                              hipStream_t stream) {
    const float* x        = (const float*)d_in[0];
    const float* y        = (const float*)d_in[1];
    const float* pos      = (const float*)d_in[2];
    const float* sqkv_w   = (const float*)d_in[3];
    const float* sqkv_b   = (const float*)d_in[4];
    const float* so_w     = (const float*)d_in[5];
    const float* so_b     = (const float*)d_in[6];
    const float* cqkv_w   = (const float*)d_in[7];
    const float* cqkv_b   = (const float*)d_in[8];
    const float* co_w     = (const float*)d_in[9];
    const float* co_b     = (const float*)d_in[10];
    const float* ffn_w1   = (const float*)d_in[11];
    const float* ffn_b1   = (const float*)d_in[12];
    const float* ffn_w2   = (const float*)d_in[13];
    const float* ffn_b2   = (const float*)d_in[14];
    const float* ln_g     = (const float*)d_in[15];
    const float* ln_b     = (const float*)d_in[16];

    char* w = (char*)d_ws;
    auto alloc = [&](size_t bytes) { char* p = w; w += (bytes + 255) & ~(size_t)255; return p; };

    u16* wt_sqkv = (u16*)alloc(18ull * 65536 * 2);
    u16* wt_so   = (u16*)alloc(6ull  * 65536 * 2);
    u16* wt_cqkv = (u16*)alloc(18ull * 65536 * 2);
    u16* wt_co   = (u16*)alloc(6ull  * 65536 * 2);
    u16* wt_f1   = (u16*)alloc(6ull  * 262144 * 2);
    u16* wt_f2   = (u16*)alloc(6ull  * 262144 * 2);
    u16* xp      = (u16*)alloc(2097152ull * 2);
    float* hf    = (float*)alloc(1048576ull * 4);
    u16* hb      = (u16*)alloc(1048576ull * 2);
    u16* qbuf    = (u16*)alloc(1048576ull * 2);
    u16* kfm     = (u16*)alloc(2097152ull * 2);
    u16* vfm     = (u16*)alloc(2097152ull * 2);
    u16* ctx     = (u16*)alloc(1048576ull * 2);
    u16* kfm_all = (u16*)alloc(6ull * 2097152 * 2);   // per-layer cross K (24 MB)
    u16* vfm_all = (u16*)alloc(6ull * 2097152 * 2);   // per-layer cross V (24 MB)

    k_wtrans_fm<<<dim3(256, 18), 256, 0, stream>>>(sqkv_w, wt_sqkv, 256, 256);
    k_wtrans_fm<<<dim3(256, 6),  256, 0, stream>>>(so_w,   wt_so,   256, 256);
    k_wtrans_fm<<<dim3(256, 18), 256, 0, stream>>>(cqkv_w, wt_cqkv, 256, 256);
    k_wtrans_fm<<<dim3(256, 6),  256, 0, stream>>>(co_w,   wt_co,   256, 256);
    k_wtrans_fm<<<dim3(1024, 6), 256, 0, stream>>>(ffn_w1, wt_f1,   256, 1024);
    k_wtrans_fm<<<dim3(1024, 6), 256, 0, stream>>>(ffn_w2, wt_f2,   1024, 256);
    k_addpos<<<dim3(8192), 256, 0, stream>>>(x, pos, xp);
    k_inith<<<dim3(4096), 256, 0, stream>>>(y, hf, hb);
    // cross K/V for all 6 layers: layer-invariant A=xp, fused K+V per block
    k_kv_pre<<<dim3(128, 8, 6), 256, 0, stream>>>(xp, wt_cqkv, cqkv_b, kfm_all, vfm_all);

    const float qscale = 0.125f * 1.44269504f;  // 1/sqrt(64) * log2(e)

    for (int i = 0; i < 6; i++) {
        // ---- self attention ----
        k_gemm_qkv<<<dim3(64, 8, 3), 256, 0, stream>>>(hb, hb,
            wt_sqkv + (size_t)i * 3 * 65536, sqkv_b + i * 768,
            qbuf, kfm, vfm, 256, 65536, 256, qscale, 1, 2, 2048, 4096);
        k_attn<<<dim3(512), 512, 0, stream>>>(qbuf, kfm, vfm, ctx, 2048, 2048);
        k_gemm_ln<<<dim3(256), 512, 0, stream>>>(ctx, wt_so + (size_t)i * 65536,
            so_b + i * 256, hf, ln_g + (i * 3 + 0) * 256, ln_b + (i * 3 + 0) * 256,
            hf, hb, 256);

        // ---- cross attention (K/V precomputed; only q GEMM in-loop) ----
        k_gemm_qkv<<<dim3(64, 8, 1), 256, 0, stream>>>(hb, xp,
            wt_cqkv + (size_t)i * 3 * 65536, cqkv_b + i * 768,
            qbuf, kfm, vfm, 256, 65536, 256, qscale, 1, 2, 4096, 4096);
        k_attn<<<dim3(512), 512, 0, stream>>>(qbuf,
            kfm_all + (size_t)i * 2097152, vfm_all + (size_t)i * 2097152, ctx, 2048, 4096);
        k_gemm_ln<<<dim3(256), 512, 0, stream>>>(ctx, wt_co + (size_t)i * 65536,
            co_b + i * 256, hf, ln_g + (i * 3 + 1) * 256, ln_b + (i * 3 + 1) * 256,
            hf, hb, 256);

        // ---- fused FFN (round-8 proven: 16 rows/block, 256 blocks) ----
        float* dst = (i == 5) ? (float*)d_out : hf;
        k_ffn<<<dim3(256), 512, 0, stream>>>(hb, wt_f1 + (size_t)i * 262144,
            ffn_b1 + i * 1024, wt_f2 + (size_t)i * 262144, ffn_b2 + i * 256,
            hf, ln_g + (i * 3 + 2) * 256, ln_b + (i * 3 + 2) * 256, dst, hb);
    }
}